// Round 13
// baseline (23764.333 us; speedup 1.0000x reference)
//
#include <hip/hip_runtime.h>
#include <hip/hip_bf16.h>
#include <math.h>

#define B_  64
#define T_  512
#define I_  512
#define H_  1024
#define G4_ 4096
#define O_  512
#define TC_ 64             // time chunk
#define NCH (T_ / TC_)     // 8
#define WPG 16             // WGs per gbar group

typedef short  s16x8 __attribute__((ext_vector_type(8)));
typedef float  fx4   __attribute__((ext_vector_type(4)));
typedef float  fx8   __attribute__((ext_vector_type(8)));
typedef unsigned short u16;
typedef u16    u16x4 __attribute__((ext_vector_type(4)));
typedef unsigned long long u64t;

__device__ __forceinline__ u16 f2bf(float f){
  unsigned u = __float_as_uint(f);
  unsigned r = u + 0x7fffu + ((u >> 16) & 1u);   // RNE
  return (u16)(r >> 16);
}
__device__ __forceinline__ float bf2f(u16 s){ return __uint_as_float(((unsigned)s) << 16); }
__device__ __forceinline__ float sigm(float x){ return 1.0f / (1.0f + __expf(-x)); }
__device__ __forceinline__ float tanh_(float x){
  float ax = fabsf(x);
  float e  = __expf(2.0f * ax);
  float r  = 1.0f - 2.0f / (e + 1.0f);
  return copysignf(r, x);
}
__device__ __forceinline__ fx4 mfma(s16x8 a, s16x8 b, fx4 c){
  return __builtin_amdgcn_mfma_f32_16x16x32_bf16(a, b, c, 0, 0, 0);
}

// system scope (sc0+sc1): bypass L1+L2 -> L3-coherent. Writers use this.
__device__ __forceinline__ void astore32(u16* p, unsigned v){
  __hip_atomic_store((unsigned*)p, v, __ATOMIC_RELAXED, __HIP_MEMORY_SCOPE_SYSTEM);
}
__device__ __forceinline__ unsigned aload32(const unsigned* p){
  return __hip_atomic_load(p, __ATOMIC_RELAXED, __HIP_MEMORY_SCOPE_SYSTEM);
}
__device__ __forceinline__ unsigned afadd(unsigned* p){
  return __hip_atomic_fetch_add(p, 1u, __ATOMIC_RELAXED, __HIP_MEMORY_SCOPE_SYSTEM);
}
// agent scope (sc0): bypass L1, served by local XCD L2 (fills it). Readers.
// Safe here because each exchange address is read at exactly one step per
// launch (slice-rotated archive) and launches invalidate L2 (r3-r6 proven).
__device__ __forceinline__ u64t aload64_ag(const u16* p){
  return __hip_atomic_load((const u64t*)p, __ATOMIC_RELAXED, __HIP_MEMORY_SCOPE_AGENT);
}

// ---------------- prep kernels ----------------
__global__ void cvt_hilo(const float* __restrict__ src, u16* __restrict__ hi,
                         u16* __restrict__ lo, int n4){
  int i      = blockIdx.x * blockDim.x + threadIdx.x;
  int stride = gridDim.x * blockDim.x;
  for (; i < n4; i += stride){
    fx4 v = ((const fx4*)src)[i];
    u16x4 h, l;
    #pragma unroll
    for (int k = 0; k < 4; ++k){
      u16 hh = f2bf(v[k]);
      h[k] = hh;
      l[k] = f2bf(v[k] - bf2f(hh));
    }
    ((u16x4*)hi)[i] = h;
    ((u16x4*)lo)[i] = l;
  }
}

__global__ void vadd(const float* __restrict__ a, const float* __restrict__ b,
                     float* __restrict__ o, int n){
  int i = blockIdx.x * blockDim.x + threadIdx.x;
  if (i < n) o[i] = a[i] + b[i];
}

// zero: c-states, slice 0 of the 4 archive arrays, barrier state
__global__ void zero_init(float* cst1, float* cst2,
                          u16* a0, u16* a1, u16* a2, u16* a3, unsigned* bar){
  int i = blockIdx.x * blockDim.x + threadIdx.x;   // 65536 threads
  cst1[i] = 0.0f; cst2[i] = 0.0f;
  const size_t off = ((size_t)(i >> 10) * (TC_ + 1)) * H_ + (i & 1023);
  a0[off] = 0; a1[off] = 0; a2[off] = 0; a3[off] = 0;
  if (i < 4096) bar[i] = 0u;
}

// ---------------- bulk GEMM (split-bf16, 128x64 tile) ----------------
// AMODE 0: A = fp32 x at [b][c0+tl][KD]; AMODE 1: A = archive [b][(TC+1)][KD],
// slice tl+1 (slice 0 = carry). OMODE 0: xp [(tl*4+g)*H + j]*64 + b;
// OMODE 1: out[(b*T_+c0+tl)*N + n].
template<int KD, int AMODE, int OMODE>
__global__ __launch_bounds__(256)
void gemmX(const float* __restrict__ Af,
           const u16* __restrict__ Ah, const u16* __restrict__ Al,
           const u16* __restrict__ Bh, const u16* __restrict__ Bl,
           const float* __restrict__ bias,
           float* __restrict__ out, int N, int c0)
{
  __shared__ float xt[(OMODE == 0) ? 64 * 130 : 4];
  const int lane = threadIdx.x & 63;
  const int wv   = threadIdx.x >> 6;
  const int l15  = lane & 15;
  const int lhi  = lane >> 4;
  const int koff = lhi * 8;
  const int mb   = blockIdx.x * 128;
  const int nb   = blockIdx.y * 64;
  const int r0   = mb + wv * 32 + l15;

  fx4 acc[2][4] = {};
  for (int kt = 0; kt < KD / 32; ++kt){
    const int kb = kt * 32 + koff;
    s16x8 ah[2], al[2];
    #pragma unroll
    for (int mi = 0; mi < 2; ++mi){
      const int r  = r0 + mi * 16;
      const int b  = r & 63;
      const int tl = r >> 6;
      if (AMODE == 0){
        const float* p = Af + ((size_t)b * T_ + c0 + tl) * KD + kb;
        fx8 v = *reinterpret_cast<const fx8*>(p);
        #pragma unroll
        for (int i = 0; i < 8; ++i){
          u16 h = f2bf(v[i]);
          ah[mi][i] = (short)h;
          al[mi][i] = (short)f2bf(v[i] - bf2f(h));
        }
      } else {
        const size_t ao = ((size_t)b * (TC_ + 1) + tl + 1) * KD + kb;
        ah[mi] = *reinterpret_cast<const s16x8*>(Ah + ao);
        al[mi] = *reinterpret_cast<const s16x8*>(Al + ao);
      }
    }
    #pragma unroll
    for (int c = 0; c < 4; ++c){
      const size_t wo = (size_t)(nb + c * 16 + l15) * KD + kb;
      s16x8 bh = *reinterpret_cast<const s16x8*>(Bh + wo);
      s16x8 bl = *reinterpret_cast<const s16x8*>(Bl + wo);
      #pragma unroll
      for (int mi = 0; mi < 2; ++mi){
        acc[mi][c] = mfma(ah[mi], bh, acc[mi][c]);
        acc[mi][c] = mfma(ah[mi], bl, acc[mi][c]);
        acc[mi][c] = mfma(al[mi], bh, acc[mi][c]);
      }
    }
  }

  if (OMODE == 0){
    #pragma unroll
    for (int c = 0; c < 4; ++c){
      const int nloc = c * 16 + l15;
      const float bv = bias[nb + nloc];
      #pragma unroll
      for (int mi = 0; mi < 2; ++mi)
        #pragma unroll
        for (int r = 0; r < 4; ++r)
          xt[nloc * 130 + wv * 32 + mi * 16 + lhi * 4 + r] = acc[mi][c][r] + bv;
    }
    __syncthreads();
    const int mloc = threadIdx.x & 127;
    const int b    = mloc & 63;
    const int tl   = blockIdx.x * 2 + (mloc >> 6);
    #pragma unroll
    for (int it = 0; it < 32; ++it){
      const int nloc = (threadIdx.x >> 7) + it * 2;
      const int n = nb + nloc;
      const int g = n >> 10;
      const int j = n & 1023;
      out[((size_t)(tl * 4 + g) * H_ + j) * 64 + b] = xt[nloc * 130 + mloc];
    }
  } else {
    #pragma unroll
    for (int c = 0; c < 4; ++c){
      const int n = nb + c * 16 + l15;
      const float bv = bias[n];
      #pragma unroll
      for (int mi = 0; mi < 2; ++mi)
        #pragma unroll
        for (int r = 0; r < 4; ++r){
          const int m  = mb + wv * 32 + mi * 16 + lhi * 4 + r;
          const int b  = m & 63;
          const int tl = m >> 6;
          out[((size_t)b * T_ + c0 + tl) * (size_t)N + n] = acc[mi][c][r] + bv;
        }
    }
  }
}

// ---------------- two-level grid barrier (relaxed atomics, r7-proven) ----------
__device__ __forceinline__ void gbar(unsigned* bar, int gid, unsigned ep, int ngrp){
  if (afadd(&bar[gid * 32]) == WPG - 1u){
    __hip_atomic_store(&bar[gid * 32], 0u, __ATOMIC_RELAXED, __HIP_MEMORY_SCOPE_SYSTEM);
    if (afadd(&bar[512]) == (unsigned)(ngrp - 1)){
      __hip_atomic_store(&bar[512], 0u, __ATOMIC_RELAXED, __HIP_MEMORY_SCOPE_SYSTEM);
      astore32((u16*)&bar[544], ep);
    } else {
      while (aload32(&bar[544]) != ep) __builtin_amdgcn_s_sleep(1);
    }
    astore32((u16*)&bar[1024 + gid * 32], ep);
  } else {
    while (aload32(&bar[1024 + gid * 32]) != ep) __builtin_amdgcn_s_sleep(1);
  }
}

// ---------------- persistent dual-layer LSTM chunk (LDS-W, min-sync) ----------
// WG = 32 gate-cols (8 units x 4 gates) x all 64 rows; 128 WGs/layer. W slice
// (hi+lo, 128 KB) staged to LDS once per chunk. Wave (mt,ct) = rows mt*16..+16,
// cols ct*16..+16, FULL K=1024 -> no cross-wave K reduce; only an 8.4 KB gate
// gather. h exchange = the archive itself [B][TC+1][H]: writes sc1 (L3), reads
// agent sc0 (local-L2 auto-mirror; slice addresses unique per launch).
// Per step: 3 syncthreads + 1 gbar.
__global__ __launch_bounds__(512)
void lstm_pd(int mode, unsigned ep0, int ngrp,
    const u16* __restrict__ W1h, const u16* __restrict__ W1l,
    const float* __restrict__ xp1, float* __restrict__ cst1,
    u16* __restrict__ ha1h, u16* __restrict__ ha1l,
    const u16* __restrict__ W2h, const u16* __restrict__ W2l,
    const float* __restrict__ xp2, float* __restrict__ cst2,
    u16* __restrict__ ha2h, u16* __restrict__ ha2l,
    unsigned* __restrict__ bar)
{
  __shared__ short lw[2][32768];     // [hi/lo][32 cols x 1024 k] swizzled, 128 KB
  __shared__ float gates[64 * 33];   // [row][gate*8+unit], 8.4 KB

  int part, bx;
  if (mode == 3){ part = blockIdx.x >> 7; bx = blockIdx.x & 127; }
  else          { part = mode - 1;        bx = blockIdx.x; }
  const int gid = blockIdx.x >> 4;
  const int jb  = bx * 8;                 // unit base

  const u16*   Wh  = part ? W2h  : W1h;
  const u16*   Wl  = part ? W2l  : W1l;
  const float* xp  = part ? xp2  : xp1;
  float*       cst = part ? cst2 : cst1;
  u16*         hah = part ? ha2h : ha1h;
  u16*         hal = part ? ha2l : ha1l;

  const int tid  = threadIdx.x;
  const int lane = tid & 63;
  const int wv   = tid >> 6;
  const int l15  = lane & 15;
  const int lhi  = lane >> 4;
  const int mt   = wv & 3;                // row tile (16 rows)
  const int ct   = wv >> 2;               // col tile (16 gate-cols)

  // ---- stage W slice into LDS (once per chunk) ----
  // col c in [0,32): gate = c>>3, unit = jb + (c&7); row bytes 2048, XOR swizzle
  #pragma unroll
  for (int arr = 0; arr < 2; ++arr){
    const u16* Wg = arr ? Wl : Wh;
    char* dstb = (char*)lw[arr];
    for (int i = tid; i < 4096; i += 512){
      const int col    = i >> 7;
      const int within = (i & 127) * 16;
      const int grow   = (col >> 3) * H_ + jb + (col & 7);
      s16x8 v = *reinterpret_cast<const s16x8*>(Wg + (size_t)grow * H_ + (within >> 1));
      *reinterpret_cast<s16x8*>(dstb + col * 2048 + (within ^ ((col & 7) << 4))) = v;
    }
  }
  __syncthreads();

  // epilogue identity: tid<256 -> (batch row eb, unit pair 2*e2, 2*e2+1)
  const int eb = tid & 63;
  const int e2 = tid >> 6;                // 0..3 when tid<256
  const int j0 = jb + 2 * e2;
  float cva = 0.0f, cvb = 0.0f;
  if (tid < 256){
    cva = cst[(size_t)j0 * B_ + eb];
    cvb = cst[(size_t)(j0 + 1) * B_ + eb];
  }

  // GEMM constants
  const int arow = mt * 16 + l15;                       // batch row
  const size_t abase = (size_t)arow * (TC_ + 1) * H_;   // archive row base
  const int wcol = ct * 16 + l15;                       // W col 0..31
  const char* wb_h = (const char*)lw[0] + wcol * 2048;
  const char* wb_l = (const char*)lw[1] + wcol * 2048;
  const int wswz = (wcol & 7) << 4;

  for (int tl = 0; tl < TC_; ++tl){
    // xp prefetch (coalesced over b), overlaps GEMM
    float xq0[4], xq1[4];
    if (tid < 256){
      #pragma unroll
      for (int g = 0; g < 4; ++g){
        const float* xr = xp + ((size_t)(tl * 4 + g) * H_ + j0) * 64 + eb;
        xq0[g] = xr[0];
        xq1[g] = xr[64];
      }
    }

    // ---- GEMM: full K=1024 per wave; h agent-reads (XCD-L2 cached), W LDS ----
    const u16* hbh = hah + abase + (size_t)tl * H_;
    const u16* hbl = hal + abase + (size_t)tl * H_;
    fx4 a4[4] = {};
    #pragma unroll 8
    for (int ks = 0; ks < 32; ++ks){
      const int k = ks * 32 + lhi * 8;
      union { u64t u[2]; s16x8 v; } ua, ul;
      ua.u[0] = aload64_ag(hbh + k);  ua.u[1] = aload64_ag(hbh + k + 4);
      ul.u[0] = aload64_ag(hbl + k);  ul.u[1] = aload64_ag(hbl + k + 4);
      const int wo = (ks * 64 + lhi * 16) ^ wswz;
      s16x8 bh = *reinterpret_cast<const s16x8*>(wb_h + wo);
      s16x8 bl = *reinterpret_cast<const s16x8*>(wb_l + wo);
      fx4 t = a4[ks & 3];
      t = mfma(ua.v, bh, t);
      t = mfma(ua.v, bl, t);
      t = mfma(ul.v, bh, t);
      a4[ks & 3] = t;
    }
    const fx4 acc = (a4[0] + a4[1]) + (a4[2] + a4[3]);

    // ---- gate gather: D col = lane&15, row = (lane>>4)*4 + r ----
    #pragma unroll
    for (int r = 0; r < 4; ++r)
      gates[(mt * 16 + lhi * 4 + r) * 33 + wcol] = acc[r];
    __syncthreads();

    if (tid < 256){
      const int u0 = 2 * e2;
      const float* gr = gates + eb * 33;
      float iv = sigm (gr[u0]          + xq0[0]);
      float fv = sigm (gr[8 + u0]      + xq0[1]);
      float gv = tanh_(gr[16 + u0]     + xq0[2]);
      float ov = sigm (gr[24 + u0]     + xq0[3]);
      float cn = fv * cva + iv * gv;
      float h0 = ov * tanh_(cn);
      cva = cn;
      iv = sigm (gr[u0 + 1]        + xq1[0]);
      fv = sigm (gr[8 + u0 + 1]    + xq1[1]);
      gv = tanh_(gr[16 + u0 + 1]   + xq1[2]);
      ov = sigm (gr[24 + u0 + 1]   + xq1[3]);
      cn = fv * cvb + iv * gv;
      float h1 = ov * tanh_(cn);
      cvb = cn;

      u16 h0h = f2bf(h0), h0l = f2bf(h0 - bf2f(h0h));
      u16 h1h = f2bf(h1), h1l = f2bf(h1 - bf2f(h1h));
      const unsigned ph = (unsigned)h0h | ((unsigned)h1h << 16);
      const unsigned pl = (unsigned)h0l | ((unsigned)h1l << 16);
      const size_t ai = ((size_t)eb * (TC_ + 1) + tl + 1) * H_ + j0;
      astore32(hah + ai, ph);
      astore32(hal + ai, pl);
      if (tl == TC_ - 1){                 // carry for next chunk (slice 0)
        const size_t a0 = ((size_t)eb * (TC_ + 1)) * H_ + j0;
        astore32(hah + a0, ph);
        astore32(hal + a0, pl);
      }
    }

    __syncthreads();                      // gates reuse + vmcnt drain
    if (tid == 0) gbar(bar, gid, ep0 + tl + 1, ngrp);
    __syncthreads();
  }
  if (tid < 256){
    cst[(size_t)j0 * B_ + eb]       = cva;
    cst[(size_t)(j0 + 1) * B_ + eb] = cvb;
  }
}

// ---------------- host launch ----------------
extern "C" void kernel_launch(void* const* d_in, const int* in_sizes, int n_in,
                              void* d_out, int out_size, void* d_ws, size_t ws_size,
                              hipStream_t stream)
{
  const float* x    = (const float*)d_in[0];
  const float* Wih1 = (const float*)d_in[1];
  const float* Whh1 = (const float*)d_in[2];
  const float* bih1 = (const float*)d_in[3];
  const float* bhh1 = (const float*)d_in[4];
  const float* Wih2 = (const float*)d_in[5];
  const float* Whh2 = (const float*)d_in[6];
  const float* bih2 = (const float*)d_in[7];
  const float* bhh2 = (const float*)d_in[8];
  const float* fcW  = (const float*)d_in[9];
  const float* fcb  = (const float*)d_in[10];
  float* out = (float*)d_out;
  (void)in_sizes; (void)n_in; (void)out_size; (void)ws_size;

  char* base = (char*)d_ws;
  size_t off = 0;
  auto alloc = [&](size_t bytes) -> void* {
    void* p = base + off;
    off = (off + bytes + 255) & ~(size_t)255;
    return p;
  };
  u16* Wih1_hi = (u16*)alloc((size_t)G4_ * I_ * 2);
  u16* Wih1_lo = (u16*)alloc((size_t)G4_ * I_ * 2);
  u16* Whh1_hi = (u16*)alloc((size_t)G4_ * H_ * 2);
  u16* Whh1_lo = (u16*)alloc((size_t)G4_ * H_ * 2);
  u16* Wih2_hi = (u16*)alloc((size_t)G4_ * H_ * 2);
  u16* Wih2_lo = (u16*)alloc((size_t)G4_ * H_ * 2);
  u16* Whh2_hi = (u16*)alloc((size_t)G4_ * H_ * 2);
  u16* Whh2_lo = (u16*)alloc((size_t)G4_ * H_ * 2);
  u16* fcW_hi  = (u16*)alloc((size_t)O_ * H_ * 2);
  u16* fcW_lo  = (u16*)alloc((size_t)O_ * H_ * 2);
  float* bsum1 = (float*)alloc((size_t)G4_ * 4);
  float* bsum2 = (float*)alloc((size_t)G4_ * 4);
  float* cst1  = (float*)alloc((size_t)B_ * H_ * 4);
  float* cst2  = (float*)alloc((size_t)B_ * H_ * 4);
  u16* h1s_hi = (u16*)alloc((size_t)B_ * (TC_ + 1) * H_ * 2);  // archive = exchange
  u16* h1s_lo = (u16*)alloc((size_t)B_ * (TC_ + 1) * H_ * 2);
  u16* h2s_hi = (u16*)alloc((size_t)B_ * (TC_ + 1) * H_ * 2);
  u16* h2s_lo = (u16*)alloc((size_t)B_ * (TC_ + 1) * H_ * 2);
  float* xp1  = (float*)alloc((size_t)TC_ * G4_ * B_ * 4);
  float* xp2  = (float*)alloc((size_t)TC_ * G4_ * B_ * 4);
  unsigned* bar = (unsigned*)alloc(4096 * 4);

  // ---- prep ----
  cvt_hilo<<<512, 256, 0, stream>>>(Wih1, Wih1_hi, Wih1_lo, G4_ * I_ / 4);
  cvt_hilo<<<512, 256, 0, stream>>>(Whh1, Whh1_hi, Whh1_lo, G4_ * H_ / 4);
  cvt_hilo<<<512, 256, 0, stream>>>(Wih2, Wih2_hi, Wih2_lo, G4_ * H_ / 4);
  cvt_hilo<<<512, 256, 0, stream>>>(Whh2, Whh2_hi, Whh2_lo, G4_ * H_ / 4);
  cvt_hilo<<<256, 256, 0, stream>>>(fcW,  fcW_hi,  fcW_lo,  O_ * H_ / 4);
  vadd<<<16, 256, 0, stream>>>(bih1, bhh1, bsum1, G4_);
  vadd<<<16, 256, 0, stream>>>(bih2, bhh2, bsum2, G4_);
  zero_init<<<256, 256, 0, stream>>>(cst1, cst2, h1s_hi, h1s_lo, h2s_hi, h2s_lo, bar);

  const dim3 gX(32, 64);
  const dim3 gF(32, 8);

  gemmX<I_, 0, 0><<<gX, 256, 0, stream>>>(
      x, nullptr, nullptr, Wih1_hi, Wih1_lo, bsum1, xp1, G4_, 0);

  unsigned ep = 0;
  for (int c = 0; c <= NCH; ++c){
    const int mode = ((c < NCH) ? 1 : 0) | ((c >= 1) ? 2 : 0);
    const int nwg  = (mode == 3) ? 256 : 128;
    int ngrp = nwg / WPG;
    {
      void* args[] = { (void*)&mode, (void*)&ep, (void*)&ngrp,
                       (void*)&Whh1_hi, (void*)&Whh1_lo, (void*)&xp1, (void*)&cst1,
                       (void*)&h1s_hi, (void*)&h1s_lo,
                       (void*)&Whh2_hi, (void*)&Whh2_lo, (void*)&xp2, (void*)&cst2,
                       (void*)&h2s_hi, (void*)&h2s_lo,
                       (void*)&bar };
      hipLaunchCooperativeKernel((const void*)lstm_pd, dim3(nwg), dim3(512),
                                 args, 0, stream);
      ep += TC_;
    }
    if (c < NCH)
      gemmX<H_, 1, 0><<<gX, 256, 0, stream>>>(
          nullptr, h1s_hi, h1s_lo, Wih2_hi, Wih2_lo, bsum2, xp2, G4_, 0);
    if (c + 1 < NCH)
      gemmX<I_, 0, 0><<<gX, 256, 0, stream>>>(
          x, nullptr, nullptr, Wih1_hi, Wih1_lo, bsum1, xp1, G4_, (c + 1) * TC_);
    if (c >= 1)
      gemmX<H_, 1, 1><<<gF, 256, 0, stream>>>(
          nullptr, h2s_hi, h2s_lo, fcW_hi, fcW_lo, fcb, out, O_, (c - 1) * TC_);
  }
}

// Round 14
// 15872.679 us; speedup vs baseline: 1.4972x; 1.4972x over previous
//
#include <hip/hip_runtime.h>
#include <hip/hip_bf16.h>
#include <math.h>

#define B_  64
#define T_  512
#define I_  512
#define H_  1024
#define G4_ 4096
#define O_  512
#define TC_ 64             // time chunk
#define NCH (T_ / TC_)     // 8
#define WPG 16             // WGs per gbar group

typedef short  s16x8 __attribute__((ext_vector_type(8)));
typedef float  fx4   __attribute__((ext_vector_type(4)));
typedef float  fx8   __attribute__((ext_vector_type(8)));
typedef unsigned short u16;
typedef u16    u16x4 __attribute__((ext_vector_type(4)));
typedef unsigned long long u64t;

__device__ __forceinline__ u16 f2bf(float f){
  unsigned u = __float_as_uint(f);
  unsigned r = u + 0x7fffu + ((u >> 16) & 1u);   // RNE
  return (u16)(r >> 16);
}
__device__ __forceinline__ float bf2f(u16 s){ return __uint_as_float(((unsigned)s) << 16); }
__device__ __forceinline__ float sigm(float x){ return 1.0f / (1.0f + __expf(-x)); }
__device__ __forceinline__ float tanh_(float x){
  float ax = fabsf(x);
  float e  = __expf(2.0f * ax);
  float r  = 1.0f - 2.0f / (e + 1.0f);
  return copysignf(r, x);
}
__device__ __forceinline__ fx4 mfma(s16x8 a, s16x8 b, fx4 c){
  return __builtin_amdgcn_mfma_f32_16x16x32_bf16(a, b, c, 0, 0, 0);
}

// system scope (sc0+sc1): bypass L1+L2 -> L3-coherent. Writers use this.
__device__ __forceinline__ void astore32(u16* p, unsigned v){
  __hip_atomic_store((unsigned*)p, v, __ATOMIC_RELAXED, __HIP_MEMORY_SCOPE_SYSTEM);
}
__device__ __forceinline__ unsigned aload32(const unsigned* p){
  return __hip_atomic_load(p, __ATOMIC_RELAXED, __HIP_MEMORY_SCOPE_SYSTEM);
}
__device__ __forceinline__ unsigned afadd(unsigned* p){
  return __hip_atomic_fetch_add(p, 1u, __ATOMIC_RELAXED, __HIP_MEMORY_SCOPE_SYSTEM);
}
// agent scope (sc0): bypass L1 only; fills/served-by local XCD L2. Readers.
// Safe: each exchange address is read at exactly one step per launch
// (slice-rotated archive) and kernel-entry acquire invalidates caches (r13-proven).
__device__ __forceinline__ u64t aload64_ag(const u16* p){
  return __hip_atomic_load((const u64t*)p, __ATOMIC_RELAXED, __HIP_MEMORY_SCOPE_AGENT);
}

// ---------------- prep kernels ----------------
__global__ void cvt_hilo(const float* __restrict__ src, u16* __restrict__ hi,
                         u16* __restrict__ lo, int n4){
  int i      = blockIdx.x * blockDim.x + threadIdx.x;
  int stride = gridDim.x * blockDim.x;
  for (; i < n4; i += stride){
    fx4 v = ((const fx4*)src)[i];
    u16x4 h, l;
    #pragma unroll
    for (int k = 0; k < 4; ++k){
      u16 hh = f2bf(v[k]);
      h[k] = hh;
      l[k] = f2bf(v[k] - bf2f(hh));
    }
    ((u16x4*)hi)[i] = h;
    ((u16x4*)lo)[i] = l;
  }
}

__global__ void vadd(const float* __restrict__ a, const float* __restrict__ b,
                     float* __restrict__ o, int n){
  int i = blockIdx.x * blockDim.x + threadIdx.x;
  if (i < n) o[i] = a[i] + b[i];
}

// zero: c-states, slice 0 of the 4 archive arrays, barrier state
__global__ void zero_init(float* cst1, float* cst2,
                          u16* a0, u16* a1, u16* a2, u16* a3, unsigned* bar){
  int i = blockIdx.x * blockDim.x + threadIdx.x;   // 65536 threads
  cst1[i] = 0.0f; cst2[i] = 0.0f;
  const size_t off = ((size_t)(i >> 10) * (TC_ + 1)) * H_ + (i & 1023);
  a0[off] = 0; a1[off] = 0; a2[off] = 0; a3[off] = 0;
  if (i < 4096) bar[i] = 0u;
}

// ---------------- bulk GEMM (split-bf16, 128x64 tile) ----------------
// AMODE 0: A = fp32 x at [b][c0+tl][KD]; AMODE 1: A = archive [b][(TC+1)][KD],
// slice tl+1 (slice 0 = carry). OMODE 0: xp [(tl*4+g)*H + j]*64 + b;
// OMODE 1: out[(b*T_+c0+tl)*N + n].
template<int KD, int AMODE, int OMODE>
__global__ __launch_bounds__(256)
void gemmX(const float* __restrict__ Af,
           const u16* __restrict__ Ah, const u16* __restrict__ Al,
           const u16* __restrict__ Bh, const u16* __restrict__ Bl,
           const float* __restrict__ bias,
           float* __restrict__ out, int N, int c0)
{
  __shared__ float xt[(OMODE == 0) ? 64 * 130 : 4];
  const int lane = threadIdx.x & 63;
  const int wv   = threadIdx.x >> 6;
  const int l15  = lane & 15;
  const int lhi  = lane >> 4;
  const int koff = lhi * 8;
  const int mb   = blockIdx.x * 128;
  const int nb   = blockIdx.y * 64;
  const int r0   = mb + wv * 32 + l15;

  fx4 acc[2][4] = {};
  for (int kt = 0; kt < KD / 32; ++kt){
    const int kb = kt * 32 + koff;
    s16x8 ah[2], al[2];
    #pragma unroll
    for (int mi = 0; mi < 2; ++mi){
      const int r  = r0 + mi * 16;
      const int b  = r & 63;
      const int tl = r >> 6;
      if (AMODE == 0){
        const float* p = Af + ((size_t)b * T_ + c0 + tl) * KD + kb;
        fx8 v = *reinterpret_cast<const fx8*>(p);
        #pragma unroll
        for (int i = 0; i < 8; ++i){
          u16 h = f2bf(v[i]);
          ah[mi][i] = (short)h;
          al[mi][i] = (short)f2bf(v[i] - bf2f(h));
        }
      } else {
        const size_t ao = ((size_t)b * (TC_ + 1) + tl + 1) * KD + kb;
        ah[mi] = *reinterpret_cast<const s16x8*>(Ah + ao);
        al[mi] = *reinterpret_cast<const s16x8*>(Al + ao);
      }
    }
    #pragma unroll
    for (int c = 0; c < 4; ++c){
      const size_t wo = (size_t)(nb + c * 16 + l15) * KD + kb;
      s16x8 bh = *reinterpret_cast<const s16x8*>(Bh + wo);
      s16x8 bl = *reinterpret_cast<const s16x8*>(Bl + wo);
      #pragma unroll
      for (int mi = 0; mi < 2; ++mi){
        acc[mi][c] = mfma(ah[mi], bh, acc[mi][c]);
        acc[mi][c] = mfma(ah[mi], bl, acc[mi][c]);
        acc[mi][c] = mfma(al[mi], bh, acc[mi][c]);
      }
    }
  }

  if (OMODE == 0){
    #pragma unroll
    for (int c = 0; c < 4; ++c){
      const int nloc = c * 16 + l15;
      const float bv = bias[nb + nloc];
      #pragma unroll
      for (int mi = 0; mi < 2; ++mi)
        #pragma unroll
        for (int r = 0; r < 4; ++r)
          xt[nloc * 130 + wv * 32 + mi * 16 + lhi * 4 + r] = acc[mi][c][r] + bv;
    }
    __syncthreads();
    const int mloc = threadIdx.x & 127;
    const int b    = mloc & 63;
    const int tl   = blockIdx.x * 2 + (mloc >> 6);
    #pragma unroll
    for (int it = 0; it < 32; ++it){
      const int nloc = (threadIdx.x >> 7) + it * 2;
      const int n = nb + nloc;
      const int g = n >> 10;
      const int j = n & 1023;
      out[((size_t)(tl * 4 + g) * H_ + j) * 64 + b] = xt[nloc * 130 + mloc];
    }
  } else {
    #pragma unroll
    for (int c = 0; c < 4; ++c){
      const int n = nb + c * 16 + l15;
      const float bv = bias[n];
      #pragma unroll
      for (int mi = 0; mi < 2; ++mi)
        #pragma unroll
        for (int r = 0; r < 4; ++r){
          const int m  = mb + wv * 32 + mi * 16 + lhi * 4 + r;
          const int b  = m & 63;
          const int tl = m >> 6;
          out[((size_t)b * T_ + c0 + tl) * (size_t)N + n] = acc[mi][c][r] + bv;
        }
    }
  }
}

// ---------------- two-level grid barrier (relaxed atomics, r7-proven) ----------
__device__ __forceinline__ void gbar(unsigned* bar, int gid, unsigned ep, int ngrp){
  if (afadd(&bar[gid * 32]) == WPG - 1u){
    __hip_atomic_store(&bar[gid * 32], 0u, __ATOMIC_RELAXED, __HIP_MEMORY_SCOPE_SYSTEM);
    if (afadd(&bar[512]) == (unsigned)(ngrp - 1)){
      __hip_atomic_store(&bar[512], 0u, __ATOMIC_RELAXED, __HIP_MEMORY_SCOPE_SYSTEM);
      astore32((u16*)&bar[544], ep);
    } else {
      while (aload32(&bar[544]) != ep) __builtin_amdgcn_s_sleep(1);
    }
    astore32((u16*)&bar[1024 + gid * 32], ep);
  } else {
    while (aload32(&bar[1024 + gid * 32]) != ep) __builtin_amdgcn_s_sleep(1);
  }
}

// ---------------- persistent dual-layer LSTM chunk (LDS-W, no-dup GEMM) -------
// WG = 32 gate-cols (8 units x 4 gates) x all 64 rows; 128 WGs/layer. W slice
// (hi+lo, 128 KB) staged to LDS once per chunk. Wave (kh,mt) = rows mt*16..+16,
// ALL 32 cols, K-half kh*512: per ks 4 h-loads feed 6 MFMAs (A-frag reused by
// both col-tiles -> no duplicate h reads; 64 loads/lane/step, half of r13).
// Cross-wave reduce = single phase over kh (2 partials), red[64][66].
// h exchange = archive [B][TC+1][H]: writes sc1 (L3), reads agent sc0.
// Per step: 3 syncthreads + 1 gbar.
__global__ __launch_bounds__(512)
void lstm_pd(int mode, unsigned ep0, int ngrp,
    const u16* __restrict__ W1h, const u16* __restrict__ W1l,
    const float* __restrict__ xp1, float* __restrict__ cst1,
    u16* __restrict__ ha1h, u16* __restrict__ ha1l,
    const u16* __restrict__ W2h, const u16* __restrict__ W2l,
    const float* __restrict__ xp2, float* __restrict__ cst2,
    u16* __restrict__ ha2h, u16* __restrict__ ha2l,
    unsigned* __restrict__ bar)
{
  __shared__ short lw[2][32768];     // [hi/lo][32 cols x 1024 k] swizzled, 128 KB
  __shared__ float red[64 * 66];     // [row][col*2 + kh], 16.9 KB

  int part, bx;
  if (mode == 3){ part = blockIdx.x >> 7; bx = blockIdx.x & 127; }
  else          { part = mode - 1;        bx = blockIdx.x; }
  const int gid = blockIdx.x >> 4;
  const int jb  = bx * 8;                 // unit base

  const u16*   Wh  = part ? W2h  : W1h;
  const u16*   Wl  = part ? W2l  : W1l;
  const float* xp  = part ? xp2  : xp1;
  float*       cst = part ? cst2 : cst1;
  u16*         hah = part ? ha2h : ha1h;
  u16*         hal = part ? ha2l : ha1l;

  const int tid  = threadIdx.x;
  const int lane = tid & 63;
  const int wv   = tid >> 6;
  const int l15  = lane & 15;
  const int lhi  = lane >> 4;
  const int mt   = wv & 3;                // row tile (16 rows)
  const int kh   = wv >> 2;               // K-half (512)

  // ---- stage W slice into LDS (once per chunk) ----
  // col c in [0,32): gate = c>>3, unit = jb + (c&7); 2048 B/col, XOR swizzle
  #pragma unroll
  for (int arr = 0; arr < 2; ++arr){
    const u16* Wg = arr ? Wl : Wh;
    char* dstb = (char*)lw[arr];
    for (int i = tid; i < 4096; i += 512){
      const int col    = i >> 7;
      const int within = (i & 127) * 16;
      const int grow   = (col >> 3) * H_ + jb + (col & 7);
      s16x8 v = *reinterpret_cast<const s16x8*>(Wg + (size_t)grow * H_ + (within >> 1));
      *reinterpret_cast<s16x8*>(dstb + col * 2048 + (within ^ ((col & 7) << 4))) = v;
    }
  }
  __syncthreads();

  // epilogue identity: tid<256 -> (batch row eb, unit pair 2*e2, 2*e2+1)
  const int eb = tid & 63;
  const int e2 = tid >> 6;                // 0..3 when tid<256
  const int j0 = jb + 2 * e2;
  float cva = 0.0f, cvb = 0.0f;
  if (tid < 256){
    cva = cst[(size_t)j0 * B_ + eb];
    cvb = cst[(size_t)(j0 + 1) * B_ + eb];
  }

  // GEMM constants
  const int arow = mt * 16 + l15;                       // batch row
  const size_t abase = (size_t)arow * (TC_ + 1) * H_;   // archive row base
  const int kbase  = kh * 512 + lhi * 8;                // u16 k index
  const int wbase  = kh * 1024 + lhi * 16;              // byte offset in col row
  const char* wh0 = (const char*)lw[0] + (l15)      * 2048;
  const char* wl0 = (const char*)lw[1] + (l15)      * 2048;
  const char* wh1 = (const char*)lw[0] + (16 + l15) * 2048;
  const char* wl1 = (const char*)lw[1] + (16 + l15) * 2048;
  const int swz0 = (l15 & 7) << 4;
  const int swz1 = ((16 + l15) & 7) << 4;

  for (int tl = 0; tl < TC_; ++tl){
    // xp prefetch (coalesced over b), overlaps GEMM
    float xq0[4], xq1[4];
    if (tid < 256){
      #pragma unroll
      for (int g = 0; g < 4; ++g){
        const float* xr = xp + ((size_t)(tl * 4 + g) * H_ + j0) * 64 + eb;
        xq0[g] = xr[0];
        xq1[g] = xr[64];
      }
    }

    // ---- GEMM: rows mt*16..+16, cols 0..31, K-half kh*512 ----
    const u16* hbh = hah + abase + (size_t)tl * H_ + kbase;
    const u16* hbl = hal + abase + (size_t)tl * H_ + kbase;
    fx4 acc0 = {}, acc1 = {};
    #pragma unroll 4
    for (int ks = 0; ks < 16; ++ks){
      const int k = ks * 32;
      union { u64t u[2]; s16x8 v; } ua, ul;
      ua.u[0] = aload64_ag(hbh + k);  ua.u[1] = aload64_ag(hbh + k + 4);
      ul.u[0] = aload64_ag(hbl + k);  ul.u[1] = aload64_ag(hbl + k + 4);
      const int wo = wbase + ks * 64;
      s16x8 b0h = *reinterpret_cast<const s16x8*>(wh0 + (wo ^ swz0));
      s16x8 b0l = *reinterpret_cast<const s16x8*>(wl0 + (wo ^ swz0));
      s16x8 b1h = *reinterpret_cast<const s16x8*>(wh1 + (wo ^ swz1));
      s16x8 b1l = *reinterpret_cast<const s16x8*>(wl1 + (wo ^ swz1));
      acc0 = mfma(ua.v, b0h, acc0);
      acc0 = mfma(ua.v, b0l, acc0);
      acc0 = mfma(ul.v, b0h, acc0);
      acc1 = mfma(ua.v, b1h, acc1);
      acc1 = mfma(ua.v, b1l, acc1);
      acc1 = mfma(ul.v, b1h, acc1);
    }

    // ---- partials -> LDS: red[row][col*2 + kh]; D col=l15, row=lhi*4+r ----
    #pragma unroll
    for (int r = 0; r < 4; ++r){
      const int row = mt * 16 + lhi * 4 + r;
      red[row * 66 + (l15) * 2 + kh]      = acc0[r];
      red[row * 66 + (16 + l15) * 2 + kh] = acc1[r];
    }
    __syncthreads();

    if (tid < 256){
      const int u0 = 2 * e2;
      const float* gr = red + eb * 66;
      float i0 = gr[(u0) * 2]          + gr[(u0) * 2 + 1];
      float f0 = gr[(8 + u0) * 2]      + gr[(8 + u0) * 2 + 1];
      float g0 = gr[(16 + u0) * 2]     + gr[(16 + u0) * 2 + 1];
      float o0 = gr[(24 + u0) * 2]     + gr[(24 + u0) * 2 + 1];
      float i1 = gr[(u0 + 1) * 2]      + gr[(u0 + 1) * 2 + 1];
      float f1 = gr[(8 + u0 + 1) * 2]  + gr[(8 + u0 + 1) * 2 + 1];
      float g1 = gr[(16 + u0 + 1) * 2] + gr[(16 + u0 + 1) * 2 + 1];
      float o1 = gr[(24 + u0 + 1) * 2] + gr[(24 + u0 + 1) * 2 + 1];

      float iv = sigm (i0 + xq0[0]);
      float fv = sigm (f0 + xq0[1]);
      float gv = tanh_(g0 + xq0[2]);
      float ov = sigm (o0 + xq0[3]);
      float cn = fv * cva + iv * gv;
      float h0 = ov * tanh_(cn);
      cva = cn;
      iv = sigm (i1 + xq1[0]);
      fv = sigm (f1 + xq1[1]);
      gv = tanh_(g1 + xq1[2]);
      ov = sigm (o1 + xq1[3]);
      cn = fv * cvb + iv * gv;
      float h1 = ov * tanh_(cn);
      cvb = cn;

      u16 h0h = f2bf(h0), h0l = f2bf(h0 - bf2f(h0h));
      u16 h1h = f2bf(h1), h1l = f2bf(h1 - bf2f(h1h));
      const unsigned ph = (unsigned)h0h | ((unsigned)h1h << 16);
      const unsigned pl = (unsigned)h0l | ((unsigned)h1l << 16);
      const size_t ai = ((size_t)eb * (TC_ + 1) + tl + 1) * H_ + j0;
      astore32(hah + ai, ph);
      astore32(hal + ai, pl);
      if (tl == TC_ - 1){                 // carry for next chunk (slice 0)
        const size_t a0 = ((size_t)eb * (TC_ + 1)) * H_ + j0;
        astore32(hah + a0, ph);
        astore32(hal + a0, pl);
      }
    }

    __syncthreads();                      // red reuse + vmcnt drain
    if (tid == 0) gbar(bar, gid, ep0 + tl + 1, ngrp);
    __syncthreads();
  }
  if (tid < 256){
    cst[(size_t)j0 * B_ + eb]       = cva;
    cst[(size_t)(j0 + 1) * B_ + eb] = cvb;
  }
}

// ---------------- host launch ----------------
extern "C" void kernel_launch(void* const* d_in, const int* in_sizes, int n_in,
                              void* d_out, int out_size, void* d_ws, size_t ws_size,
                              hipStream_t stream)
{
  const float* x    = (const float*)d_in[0];
  const float* Wih1 = (const float*)d_in[1];
  const float* Whh1 = (const float*)d_in[2];
  const float* bih1 = (const float*)d_in[3];
  const float* bhh1 = (const float*)d_in[4];
  const float* Wih2 = (const float*)d_in[5];
  const float* Whh2 = (const float*)d_in[6];
  const float* bih2 = (const float*)d_in[7];
  const float* bhh2 = (const float*)d_in[8];
  const float* fcW  = (const float*)d_in[9];
  const float* fcb  = (const float*)d_in[10];
  float* out = (float*)d_out;
  (void)in_sizes; (void)n_in; (void)out_size; (void)ws_size;

  char* base = (char*)d_ws;
  size_t off = 0;
  auto alloc = [&](size_t bytes) -> void* {
    void* p = base + off;
    off = (off + bytes + 255) & ~(size_t)255;
    return p;
  };
  u16* Wih1_hi = (u16*)alloc((size_t)G4_ * I_ * 2);
  u16* Wih1_lo = (u16*)alloc((size_t)G4_ * I_ * 2);
  u16* Whh1_hi = (u16*)alloc((size_t)G4_ * H_ * 2);
  u16* Whh1_lo = (u16*)alloc((size_t)G4_ * H_ * 2);
  u16* Wih2_hi = (u16*)alloc((size_t)G4_ * H_ * 2);
  u16* Wih2_lo = (u16*)alloc((size_t)G4_ * H_ * 2);
  u16* Whh2_hi = (u16*)alloc((size_t)G4_ * H_ * 2);
  u16* Whh2_lo = (u16*)alloc((size_t)G4_ * H_ * 2);
  u16* fcW_hi  = (u16*)alloc((size_t)O_ * H_ * 2);
  u16* fcW_lo  = (u16*)alloc((size_t)O_ * H_ * 2);
  float* bsum1 = (float*)alloc((size_t)G4_ * 4);
  float* bsum2 = (float*)alloc((size_t)G4_ * 4);
  float* cst1  = (float*)alloc((size_t)B_ * H_ * 4);
  float* cst2  = (float*)alloc((size_t)B_ * H_ * 4);
  u16* h1s_hi = (u16*)alloc((size_t)B_ * (TC_ + 1) * H_ * 2);  // archive = exchange
  u16* h1s_lo = (u16*)alloc((size_t)B_ * (TC_ + 1) * H_ * 2);
  u16* h2s_hi = (u16*)alloc((size_t)B_ * (TC_ + 1) * H_ * 2);
  u16* h2s_lo = (u16*)alloc((size_t)B_ * (TC_ + 1) * H_ * 2);
  float* xp1  = (float*)alloc((size_t)TC_ * G4_ * B_ * 4);
  float* xp2  = (float*)alloc((size_t)TC_ * G4_ * B_ * 4);
  unsigned* bar = (unsigned*)alloc(4096 * 4);

  // ---- prep ----
  cvt_hilo<<<512, 256, 0, stream>>>(Wih1, Wih1_hi, Wih1_lo, G4_ * I_ / 4);
  cvt_hilo<<<512, 256, 0, stream>>>(Whh1, Whh1_hi, Whh1_lo, G4_ * H_ / 4);
  cvt_hilo<<<512, 256, 0, stream>>>(Wih2, Wih2_hi, Wih2_lo, G4_ * H_ / 4);
  cvt_hilo<<<512, 256, 0, stream>>>(Whh2, Whh2_hi, Whh2_lo, G4_ * H_ / 4);
  cvt_hilo<<<256, 256, 0, stream>>>(fcW,  fcW_hi,  fcW_lo,  O_ * H_ / 4);
  vadd<<<16, 256, 0, stream>>>(bih1, bhh1, bsum1, G4_);
  vadd<<<16, 256, 0, stream>>>(bih2, bhh2, bsum2, G4_);
  zero_init<<<256, 256, 0, stream>>>(cst1, cst2, h1s_hi, h1s_lo, h2s_hi, h2s_lo, bar);

  const dim3 gX(32, 64);
  const dim3 gF(32, 8);

  gemmX<I_, 0, 0><<<gX, 256, 0, stream>>>(
      x, nullptr, nullptr, Wih1_hi, Wih1_lo, bsum1, xp1, G4_, 0);

  unsigned ep = 0;
  for (int c = 0; c <= NCH; ++c){
    const int mode = ((c < NCH) ? 1 : 0) | ((c >= 1) ? 2 : 0);
    const int nwg  = (mode == 3) ? 256 : 128;
    int ngrp = nwg / WPG;
    {
      void* args[] = { (void*)&mode, (void*)&ep, (void*)&ngrp,
                       (void*)&Whh1_hi, (void*)&Whh1_lo, (void*)&xp1, (void*)&cst1,
                       (void*)&h1s_hi, (void*)&h1s_lo,
                       (void*)&Whh2_hi, (void*)&Whh2_lo, (void*)&xp2, (void*)&cst2,
                       (void*)&h2s_hi, (void*)&h2s_lo,
                       (void*)&bar };
      hipLaunchCooperativeKernel((const void*)lstm_pd, dim3(nwg), dim3(512),
                                 args, 0, stream);
      ep += TC_;
    }
    if (c < NCH)
      gemmX<H_, 1, 0><<<gX, 256, 0, stream>>>(
          nullptr, h1s_hi, h1s_lo, Wih2_hi, Wih2_lo, bsum2, xp2, G4_, 0);
    if (c + 1 < NCH)
      gemmX<I_, 0, 0><<<gX, 256, 0, stream>>>(
          x, nullptr, nullptr, Wih1_hi, Wih1_lo, bsum1, xp1, G4_, (c + 1) * TC_);
    if (c >= 1)
      gemmX<H_, 1, 1><<<gF, 256, 0, stream>>>(
          nullptr, h2s_hi, h2s_lo, fcW_hi, fcW_lo, fcb, out, O_, (c - 1) * TC_);
  }
}

// Round 15
// 10190.624 us; speedup vs baseline: 2.3320x; 1.5576x over previous
//
#include <hip/hip_runtime.h>
#include <hip/hip_bf16.h>
#include <math.h>

#define B_  64
#define T_  512
#define I_  512
#define H_  1024
#define G4_ 4096
#define O_  512
#define TC_ 64             // time chunk
#define NCH (T_ / TC_)     // 8
#define WPG 16             // WGs per barrier group

typedef short  s16x8 __attribute__((ext_vector_type(8)));
typedef float  fx4   __attribute__((ext_vector_type(4)));
typedef float  fx8   __attribute__((ext_vector_type(8)));
typedef unsigned short u16;
typedef u16    u16x4 __attribute__((ext_vector_type(4)));
typedef unsigned long long u64t;

__device__ __forceinline__ u16 f2bf(float f){
  unsigned u = __float_as_uint(f);
  unsigned r = u + 0x7fffu + ((u >> 16) & 1u);   // RNE
  return (u16)(r >> 16);
}
__device__ __forceinline__ float bf2f(u16 s){ return __uint_as_float(((unsigned)s) << 16); }
__device__ __forceinline__ float sigm(float x){ return 1.0f / (1.0f + __expf(-x)); }
__device__ __forceinline__ float tanh_(float x){
  float ax = fabsf(x);
  float e  = __expf(2.0f * ax);
  float r  = 1.0f - 2.0f / (e + 1.0f);
  return copysignf(r, x);
}
__device__ __forceinline__ fx4 mfma(s16x8 a, s16x8 b, fx4 c){
  return __builtin_amdgcn_mfma_f32_16x16x32_bf16(a, b, c, 0, 0, 0);
}
__device__ __forceinline__ void keepreg(s16x8& v){ asm volatile("" : "+v"(v)); }

// system-scope relaxed atomics: cache-bypass, no cache-maintenance instructions
__device__ __forceinline__ u64t aload64(const u16* p){
  return __hip_atomic_load((const u64t*)p, __ATOMIC_RELAXED, __HIP_MEMORY_SCOPE_SYSTEM);
}
__device__ __forceinline__ void astore32(u16* p, unsigned v){
  __hip_atomic_store((unsigned*)p, v, __ATOMIC_RELAXED, __HIP_MEMORY_SCOPE_SYSTEM);
}
__device__ __forceinline__ unsigned aload32(const unsigned* p){
  return __hip_atomic_load(p, __ATOMIC_RELAXED, __HIP_MEMORY_SCOPE_SYSTEM);
}
__device__ __forceinline__ unsigned afadd(unsigned* p){
  return __hip_atomic_fetch_add(p, 1u, __ATOMIC_RELAXED, __HIP_MEMORY_SCOPE_SYSTEM);
}

// ---------------- prep kernels ----------------
__global__ void cvt_hilo(const float* __restrict__ src, u16* __restrict__ hi,
                         u16* __restrict__ lo, int n4){
  int i      = blockIdx.x * blockDim.x + threadIdx.x;
  int stride = gridDim.x * blockDim.x;
  for (; i < n4; i += stride){
    fx4 v = ((const fx4*)src)[i];
    u16x4 h, l;
    #pragma unroll
    for (int k = 0; k < 4; ++k){
      u16 hh = f2bf(v[k]);
      h[k] = hh;
      l[k] = f2bf(v[k] - bf2f(hh));
    }
    ((u16x4*)hi)[i] = h;
    ((u16x4*)lo)[i] = l;
  }
}

__global__ void vadd(const float* __restrict__ a, const float* __restrict__ b,
                     float* __restrict__ o, int n){
  int i = blockIdx.x * blockDim.x + threadIdx.x;
  if (i < n) o[i] = a[i] + b[i];
}

// ---------------- bulk GEMM: 128x128 tile, LDS-staged, 4 waves ----------------
// A rows r = tl*64 + b. AMODE 0: A = fp32 x at [b][c0+tl][KD] (convert to hi/lo
// during staging); AMODE 1: A = hi/lo archive at [b*TC_+tl][KD].
// OMODE 0: xp out[((tl*4+g)*H + j)*64 + b]; OMODE 1: out[(b*T_+c0+tl)*N + n].
// LDS layout per 16-row/col block (1 KB): slot byte = l15*64 + lhi*16 -> both
// staging writes (lane slot l) and fragment ds_read_b128 are conflict-free.
template<int KD, int AMODE, int OMODE>
__global__ __launch_bounds__(256)
void gemm128(const float* __restrict__ Af,
             const u16* __restrict__ Ah, const u16* __restrict__ Al,
             const u16* __restrict__ Bh, const u16* __restrict__ Bl,
             const float* __restrict__ bias,
             float* __restrict__ out, int N, int c0)
{
  __shared__ short As0[4096], As1[4096];   // A hi/lo: 8 blocks x 512 shorts
  __shared__ short Bs0[4096], Bs1[4096];   // B hi/lo
  __shared__ float xt[(OMODE == 0) ? 64 * 130 : 4];

  const int tid  = threadIdx.x;
  const int w    = tid >> 6;
  const int lane = tid & 63;
  const int l15  = lane & 15;
  const int lhi  = lane >> 4;
  const int mb   = blockIdx.x * 128;
  const int nb   = blockIdx.y * 128;

  // staging identity: lane l -> slot l of each block (row16 = l>>2, kc = l&3)
  const int srow = lane >> 2;              // 0..15
  const int skc  = lane & 3;               // 0..3
  const int sslot = srow * 32 + skc * 8;   // short offset within block

  fx4 acc[4][4] = {};

  for (int kt = 0; kt < KD / 32; ++kt){
    const int kk = kt * 32 + skc * 8;
    __syncthreads();                       // previous iteration's reads done
    // ---- stage: wave w stages A blocks {2w,2w+1} and B blocks {2w,2w+1} ----
    #pragma unroll
    for (int bi = 0; bi < 2; ++bi){
      const int bl   = 2 * w + bi;
      const int so   = bl * 512 + sslot;
      // A block bl: rows bl*16 + srow
      const int lrow = bl * 16 + srow;
      const int r    = mb + lrow;
      const int b    = r & 63;
      const int tlr  = r >> 6;
      if (AMODE == 0){
        const float* p = Af + ((size_t)b * T_ + c0 + tlr) * KD + kk;
        fx8 v = *reinterpret_cast<const fx8*>(p);
        s16x8 hv, lv;
        #pragma unroll
        for (int q = 0; q < 8; ++q){
          u16 hh = f2bf(v[q]);
          hv[q] = (short)hh;
          lv[q] = (short)f2bf(v[q] - bf2f(hh));
        }
        *reinterpret_cast<s16x8*>(&As0[so]) = hv;
        *reinterpret_cast<s16x8*>(&As1[so]) = lv;
      } else {
        const size_t ao = ((size_t)b * TC_ + tlr) * KD + kk;
        *reinterpret_cast<s16x8*>(&As0[so]) =
            *reinterpret_cast<const s16x8*>(Ah + ao);
        *reinterpret_cast<s16x8*>(&As1[so]) =
            *reinterpret_cast<const s16x8*>(Al + ao);
      }
      // B block bl: cols nb + bl*16 + srow
      const size_t bo = (size_t)(nb + bl * 16 + srow) * KD + kk;
      *reinterpret_cast<s16x8*>(&Bs0[so]) = *reinterpret_cast<const s16x8*>(Bh + bo);
      *reinterpret_cast<s16x8*>(&Bs1[so]) = *reinterpret_cast<const s16x8*>(Bl + bo);
    }
    __syncthreads();

    // ---- MFMA: wave quadrant rows (w&1)*64, cols (w>>1)*64 ----
    const int fro = l15 * 32 + lhi * 8;
    s16x8 bhf[4], blf[4];
    #pragma unroll
    for (int j = 0; j < 4; ++j){
      const int bb = ((w >> 1) * 4 + j) * 512 + fro;
      bhf[j] = *reinterpret_cast<const s16x8*>(&Bs0[bb]);
      blf[j] = *reinterpret_cast<const s16x8*>(&Bs1[bb]);
    }
    #pragma unroll
    for (int i = 0; i < 4; ++i){
      const int ab = ((w & 1) * 4 + i) * 512 + fro;
      s16x8 ah = *reinterpret_cast<const s16x8*>(&As0[ab]);
      s16x8 al = *reinterpret_cast<const s16x8*>(&As1[ab]);
      #pragma unroll
      for (int j = 0; j < 4; ++j){
        acc[i][j] = mfma(ah, bhf[j], acc[i][j]);
        acc[i][j] = mfma(ah, blf[j], acc[i][j]);
        acc[i][j] = mfma(al, bhf[j], acc[i][j]);
      }
    }
  }

  if (OMODE == 0){
    // two row-half passes; each half = one tl, 64 b x 128 cols via xt
    #pragma unroll
    for (int p = 0; p < 2; ++p){
      __syncthreads();
      if ((w & 1) == p){
        #pragma unroll
        for (int i = 0; i < 4; ++i)
          #pragma unroll
          for (int j = 0; j < 4; ++j){
            const int col = (w >> 1) * 64 + j * 16 + l15;
            const float bv = bias[nb + col];
            #pragma unroll
            for (int r = 0; r < 4; ++r)
              xt[(i * 16 + lhi * 4 + r) * 130 + col] = acc[i][j][r] + bv;
          }
      }
      __syncthreads();
      const int tlv = (mb >> 6) + p;
      const int b   = tid & 63;
      #pragma unroll
      for (int c = 0; c < 32; ++c){
        const int col = (tid >> 6) + c * 4;
        const int n = nb + col;
        const int g = n >> 10;
        const int jj = n & 1023;
        out[((size_t)(tlv * 4 + g) * H_ + jj) * 64 + b] = xt[b * 130 + col];
      }
    }
  } else {
    #pragma unroll
    for (int j = 0; j < 4; ++j){
      const int n = nb + (w >> 1) * 64 + j * 16 + l15;
      const float bv = bias[n];
      #pragma unroll
      for (int i = 0; i < 4; ++i)
        #pragma unroll
        for (int r = 0; r < 4; ++r){
          const int m  = mb + (w & 1) * 64 + i * 16 + lhi * 4 + r;
          const int b  = m & 63;
          const int tlv = m >> 6;
          out[((size_t)b * T_ + c0 + tlv) * (size_t)N + n] = acc[i][j][r] + bv;
        }
    }
  }
}

// ---------------- two-level grid barrier (relaxed atomics, r7-proven) ----------
__device__ __forceinline__ void gbar(unsigned* bar, int gid, unsigned ep, int ngrp){
  if (afadd(&bar[gid * 32]) == WPG - 1u){
    __hip_atomic_store(&bar[gid * 32], 0u, __ATOMIC_RELAXED, __HIP_MEMORY_SCOPE_SYSTEM);
    if (afadd(&bar[512]) == (unsigned)(ngrp - 1)){
      __hip_atomic_store(&bar[512], 0u, __ATOMIC_RELAXED, __HIP_MEMORY_SCOPE_SYSTEM);
      astore32((u16*)&bar[544], ep);
    } else {
      while (aload32(&bar[544]) != ep) __builtin_amdgcn_s_sleep(1);
    }
    astore32((u16*)&bar[1024 + gid * 32], ep);
  } else {
    while (aload32(&bar[1024 + gid * 32]) != ep) __builtin_amdgcn_s_sleep(1);
  }
}

// ---------------- persistent dual-layer LSTM chunk (r10 config, best) ----------
#define RSTR 577   // LDS row stride floats (col stride 9, coprime with 32 banks)
__global__ __launch_bounds__(512) __attribute__((amdgpu_waves_per_eu(2, 2)))
void lstm_pd(int mode, unsigned ep0, int ngrp,
    const u16* __restrict__ W1h, const u16* __restrict__ W1l,
    const float* __restrict__ xp1, float* __restrict__ cst1,
    u16* __restrict__ hx1h, u16* __restrict__ hx1l,
    u16* __restrict__ ha1h, u16* __restrict__ ha1l,
    const u16* __restrict__ W2h, const u16* __restrict__ W2l,
    const float* __restrict__ xp2, float* __restrict__ cst2,
    u16* __restrict__ hx2h, u16* __restrict__ hx2l,
    u16* __restrict__ ha2h, u16* __restrict__ ha2l,
    unsigned* __restrict__ bar)
{
  __shared__ float red[16 * RSTR];

  const int x8 = blockIdx.x & 7;
  const int q  = blockIdx.x >> 3;
  int part, m4, ghi;
  if (mode == 3){ part = q & 1;    m4 = (q >> 1) & 3; ghi = q >> 3; }
  else          { part = mode - 1; m4 = q & 3;        ghi = q >> 2; }
  const int jb  = (x8 + 8 * ghi) * 32;    // unit base (0..992)
  const int mb  = m4 * 16;                // batch-row base
  const int gid = blockIdx.x >> 4;

  const u16*   Wh  = part ? W2h  : W1h;
  const u16*   Wl  = part ? W2l  : W1l;
  const float* xp  = part ? xp2  : xp1;
  float*       cst = part ? cst2 : cst1;
  u16*         hxh = part ? hx2h : hx1h;
  u16*         hxl = part ? hx2l : hx1l;
  u16*         hah = part ? ha2h : ha1h;
  u16*         hal = part ? ha2l : ha1l;

  const int tid  = threadIdx.x;
  const int lane = tid & 63;
  const int wv   = tid >> 6;              // 0..7 = K slice
  const int l15  = lane & 15;
  const int lhi  = lane >> 4;
  const int kb0  = wv * 128 + lhi * 8;

  size_t wrowR[4], wrowS[4];
  #pragma unroll
  for (int ct = 0; ct < 4; ++ct){
    const int clR = ct * 16 + l15;
    const int clS = (ct + 4) * 16 + l15;
    wrowR[ct] = (size_t)((clR >> 5) * H_ + jb + (clR & 31));
    wrowS[ct] = (size_t)((clS >> 5) * H_ + jb + (clS & 31));
  }

  s16x8 wrh[4][4], wrl[4][4];
  #pragma unroll
  for (int ct = 0; ct < 4; ++ct)
    #pragma unroll
    for (int s = 0; s < 4; ++s){
      const size_t wo = wrowR[ct] * H_ + kb0 + s * 32;
      wrh[ct][s] = *reinterpret_cast<const s16x8*>(Wh + wo);
      wrl[ct][s] = *reinterpret_cast<const s16x8*>(Wl + wo);
      keepreg(wrh[ct][s]);
      keepreg(wrl[ct][s]);
    }

  const int up = tid & 15;
  const int mm = tid >> 4;                // 0..15 when tid<256
  const int u0 = 2 * up;
  const int j0 = jb + u0;
  const int eb = mb + mm;
  float cva = 0.0f, cvb = 0.0f;
  if (tid < 256){
    cva = cst[(size_t)j0 * B_ + eb];
    cvb = cst[(size_t)(j0 + 1) * B_ + eb];
  }

  for (int tl = 0; tl < TC_; ++tl){
    const int par = tl & 1;
    const u16* rph = hxh + par * (64 * H_);
    const u16* rpl = hxl + par * (64 * H_);
    u16* nph = hxh + (par ^ 1) * (64 * H_);
    u16* npl = hxl + (par ^ 1) * (64 * H_);

    float xq0[4], xq1[4];
    if (tid < 256){
      #pragma unroll
      for (int g = 0; g < 4; ++g){
        const float* xr = xp + ((size_t)(tl * 4 + g) * H_ + j0) * 64 + eb;
        xq0[g] = xr[0];
        xq1[g] = xr[64];
      }
    }

    fx4 acc[8] = {};
    #pragma unroll
    for (int s = 0; s < 4; ++s){
      const int kb = kb0 + s * 32;
      const u16* ph = rph + (size_t)(mb + l15) * H_ + kb;
      const u16* pl = rpl + (size_t)(mb + l15) * H_ + kb;
      union { u64t u[2]; s16x8 v; } ua, ul;
      ua.u[0] = aload64(ph);  ua.u[1] = aload64(ph + 4);
      ul.u[0] = aload64(pl);  ul.u[1] = aload64(pl + 4);
      #pragma unroll
      for (int ct = 0; ct < 4; ++ct){
        acc[ct] = mfma(ua.v, wrh[ct][s], acc[ct]);
        acc[ct] = mfma(ua.v, wrl[ct][s], acc[ct]);
        acc[ct] = mfma(ul.v, wrh[ct][s], acc[ct]);
      }
      #pragma unroll
      for (int ct = 0; ct < 4; ++ct){
        const size_t wo = wrowS[ct] * H_ + kb;
        s16x8 bh = *reinterpret_cast<const s16x8*>(Wh + wo);
        s16x8 bl = *reinterpret_cast<const s16x8*>(Wl + wo);
        acc[4 + ct] = mfma(ua.v, bh, acc[4 + ct]);
        acc[4 + ct] = mfma(ua.v, bl, acc[4 + ct]);
        acc[4 + ct] = mfma(ul.v, bh, acc[4 + ct]);
      }
    }

    #pragma unroll
    for (int ct = 0; ct < 4; ++ct)
      #pragma unroll
      for (int r = 0; r < 4; ++r)
        red[(lhi * 4 + r) * RSTR + (ct * 16 + l15) * 9 + wv] = acc[ct][r];
    __syncthreads();
    float i0s = 0, i1s = 0, f0s = 0, f1s = 0;
    if (tid < 256){
      const float* r0 = red + mm * RSTR + (u0) * 9;
      const float* r1 = red + mm * RSTR + (u0 + 1) * 9;
      const float* r2 = red + mm * RSTR + (32 + u0) * 9;
      const float* r3 = red + mm * RSTR + (32 + u0 + 1) * 9;
      #pragma unroll
      for (int w = 0; w < 8; ++w){
        i0s += r0[w]; i1s += r1[w]; f0s += r2[w]; f1s += r3[w];
      }
    }
    __syncthreads();

    #pragma unroll
    for (int ct = 0; ct < 4; ++ct)
      #pragma unroll
      for (int r = 0; r < 4; ++r)
        red[(lhi * 4 + r) * RSTR + (ct * 16 + l15) * 9 + wv] = acc[4 + ct][r];
    __syncthreads();

    if (tid < 256){
      float g0s = 0, g1s = 0, o0s = 0, o1s = 0;
      const float* r0 = red + mm * RSTR + (u0) * 9;
      const float* r1 = red + mm * RSTR + (u0 + 1) * 9;
      const float* r2 = red + mm * RSTR + (32 + u0) * 9;
      const float* r3 = red + mm * RSTR + (32 + u0 + 1) * 9;
      #pragma unroll
      for (int w = 0; w < 8; ++w){
        g0s += r0[w]; g1s += r1[w]; o0s += r2[w]; o1s += r3[w];
      }
      float iv = sigm (i0s + xq0[0]);
      float fv = sigm (f0s + xq0[1]);
      float gv = tanh_(g0s + xq0[2]);
      float ov = sigm (o0s + xq0[3]);
      float cn = fv * cva + iv * gv;
      float h0 = ov * tanh_(cn);
      cva = cn;
      iv = sigm (i1s + xq1[0]);
      fv = sigm (f1s + xq1[1]);
      gv = tanh_(g1s + xq1[2]);
      ov = sigm (o1s + xq1[3]);
      cn = fv * cvb + iv * gv;
      float h1 = ov * tanh_(cn);
      cvb = cn;

      u16 h0h = f2bf(h0), h0l = f2bf(h0 - bf2f(h0h));
      u16 h1h = f2bf(h1), h1l = f2bf(h1 - bf2f(h1h));
      astore32(nph + (size_t)eb * H_ + j0, (unsigned)h0h | ((unsigned)h1h << 16));
      astore32(npl + (size_t)eb * H_ + j0, (unsigned)h0l | ((unsigned)h1l << 16));
      const size_t ai = ((size_t)eb * TC_ + tl) * H_ + j0;
      *(unsigned*)(hah + ai) = (unsigned)h0h | ((unsigned)h1h << 16);
      *(unsigned*)(hal + ai) = (unsigned)h0l | ((unsigned)h1l << 16);
    }

    __syncthreads();                      // drains vmcnt before signal
    if (tid == 0) gbar(bar, gid, ep0 + tl + 1, ngrp);
    __syncthreads();
  }
  if (tid < 256){
    cst[(size_t)j0 * B_ + eb]       = cva;
    cst[(size_t)(j0 + 1) * B_ + eb] = cvb;
  }
}

// ---------------- host launch ----------------
extern "C" void kernel_launch(void* const* d_in, const int* in_sizes, int n_in,
                              void* d_out, int out_size, void* d_ws, size_t ws_size,
                              hipStream_t stream)
{
  const float* x    = (const float*)d_in[0];
  const float* Wih1 = (const float*)d_in[1];
  const float* Whh1 = (const float*)d_in[2];
  const float* bih1 = (const float*)d_in[3];
  const float* bhh1 = (const float*)d_in[4];
  const float* Wih2 = (const float*)d_in[5];
  const float* Whh2 = (const float*)d_in[6];
  const float* bih2 = (const float*)d_in[7];
  const float* bhh2 = (const float*)d_in[8];
  const float* fcW  = (const float*)d_in[9];
  const float* fcb  = (const float*)d_in[10];
  float* out = (float*)d_out;
  (void)in_sizes; (void)n_in; (void)out_size; (void)ws_size;

  char* base = (char*)d_ws;
  size_t off = 0;
  auto alloc = [&](size_t bytes) -> void* {
    void* p = base + off;
    off = (off + bytes + 255) & ~(size_t)255;
    return p;
  };
  u16* Wih1_hi = (u16*)alloc((size_t)G4_ * I_ * 2);
  u16* Wih1_lo = (u16*)alloc((size_t)G4_ * I_ * 2);
  u16* Whh1_hi = (u16*)alloc((size_t)G4_ * H_ * 2);
  u16* Whh1_lo = (u16*)alloc((size_t)G4_ * H_ * 2);
  u16* Wih2_hi = (u16*)alloc((size_t)G4_ * H_ * 2);
  u16* Wih2_lo = (u16*)alloc((size_t)G4_ * H_ * 2);
  u16* Whh2_hi = (u16*)alloc((size_t)G4_ * H_ * 2);
  u16* Whh2_lo = (u16*)alloc((size_t)G4_ * H_ * 2);
  u16* fcW_hi  = (u16*)alloc((size_t)O_ * H_ * 2);
  u16* fcW_lo  = (u16*)alloc((size_t)O_ * H_ * 2);
  float* bsum1 = (float*)alloc((size_t)G4_ * 4);
  float* bsum2 = (float*)alloc((size_t)G4_ * 4);
  float* cst1  = (float*)alloc((size_t)B_ * H_ * 4);
  float* cst2  = (float*)alloc((size_t)B_ * H_ * 4);
  u16* hx1h = (u16*)alloc((size_t)2 * B_ * H_ * 2);
  u16* hx1l = (u16*)alloc((size_t)2 * B_ * H_ * 2);
  u16* hx2h = (u16*)alloc((size_t)2 * B_ * H_ * 2);
  u16* hx2l = (u16*)alloc((size_t)2 * B_ * H_ * 2);
  u16* h1s_hi = (u16*)alloc((size_t)B_ * TC_ * H_ * 2);
  u16* h1s_lo = (u16*)alloc((size_t)B_ * TC_ * H_ * 2);
  u16* h2s_hi = (u16*)alloc((size_t)B_ * TC_ * H_ * 2);
  u16* h2s_lo = (u16*)alloc((size_t)B_ * TC_ * H_ * 2);
  float* xp1  = (float*)alloc((size_t)TC_ * G4_ * B_ * 4);
  float* xp2  = (float*)alloc((size_t)TC_ * G4_ * B_ * 4);
  unsigned* bar = (unsigned*)alloc(2048 * 4);

  // ---- prep ----
  cvt_hilo<<<512, 256, 0, stream>>>(Wih1, Wih1_hi, Wih1_lo, G4_ * I_ / 4);
  cvt_hilo<<<512, 256, 0, stream>>>(Whh1, Whh1_hi, Whh1_lo, G4_ * H_ / 4);
  cvt_hilo<<<512, 256, 0, stream>>>(Wih2, Wih2_hi, Wih2_lo, G4_ * H_ / 4);
  cvt_hilo<<<512, 256, 0, stream>>>(Whh2, Whh2_hi, Whh2_lo, G4_ * H_ / 4);
  cvt_hilo<<<256, 256, 0, stream>>>(fcW,  fcW_hi,  fcW_lo,  O_ * H_ / 4);
  vadd<<<16, 256, 0, stream>>>(bih1, bhh1, bsum1, G4_);
  vadd<<<16, 256, 0, stream>>>(bih2, bhh2, bsum2, G4_);

  hipMemsetAsync(cst1, 0, (size_t)B_ * H_ * 4, stream);
  hipMemsetAsync(cst2, 0, (size_t)B_ * H_ * 4, stream);
  hipMemsetAsync(hx1h, 0, (size_t)2 * B_ * H_ * 2, stream);
  hipMemsetAsync(hx1l, 0, (size_t)2 * B_ * H_ * 2, stream);
  hipMemsetAsync(hx2h, 0, (size_t)2 * B_ * H_ * 2, stream);
  hipMemsetAsync(hx2l, 0, (size_t)2 * B_ * H_ * 2, stream);
  hipMemsetAsync(bar,  0, 2048 * 4, stream);

  const dim3 gX(32, 32);   // 128x128 tiles: M=4096, N=4096
  const dim3 gF(32, 4);    // N=512

  gemm128<I_, 0, 0><<<gX, 256, 0, stream>>>(
      x, nullptr, nullptr, Wih1_hi, Wih1_lo, bsum1, xp1, G4_, 0);

  unsigned ep = 0;
  for (int c = 0; c <= NCH; ++c){
    const int mode = ((c < NCH) ? 1 : 0) | ((c >= 1) ? 2 : 0);
    const int nwg  = (mode == 3) ? 256 : 128;
    int ngrp = nwg / WPG;
    {
      void* args[] = { (void*)&mode, (void*)&ep, (void*)&ngrp,
                       (void*)&Whh1_hi, (void*)&Whh1_lo, (void*)&xp1, (void*)&cst1,
                       (void*)&hx1h, (void*)&hx1l, (void*)&h1s_hi, (void*)&h1s_lo,
                       (void*)&Whh2_hi, (void*)&Whh2_lo, (void*)&xp2, (void*)&cst2,
                       (void*)&hx2h, (void*)&hx2l, (void*)&h2s_hi, (void*)&h2s_lo,
                       (void*)&bar };
      hipLaunchCooperativeKernel((const void*)lstm_pd, dim3(nwg), dim3(512),
                                 args, 0, stream);
      ep += TC_;
    }
    if (c < NCH)
      gemm128<H_, 1, 0><<<gX, 256, 0, stream>>>(
          nullptr, h1s_hi, h1s_lo, Wih2_hi, Wih2_lo, bsum2, xp2, G4_, 0);
    if (c + 1 < NCH)
      gemm128<I_, 0, 0><<<gX, 256, 0, stream>>>(
          x, nullptr, nullptr, Wih1_hi, Wih1_lo, bsum1, xp1, G4_, (c + 1) * TC_);
    if (c >= 1)
      gemm128<H_, 1, 1><<<gF, 256, 0, stream>>>(
          nullptr, h2s_hi, h2s_lo, fcW_hi, fcW_lo, fcb, out, O_, (c - 1) * TC_);
  }
}

// Round 17
// 10133.699 us; speedup vs baseline: 2.3451x; 1.0056x over previous
//
#include <hip/hip_runtime.h>
#include <hip/hip_bf16.h>
#include <math.h>

#define B_  64
#define T_  512
#define I_  512
#define H_  1024
#define G4_ 4096
#define O_  512
#define TC_ 64             // time chunk
#define NCH (T_ / TC_)     // 8
#define WPG 16             // WGs per barrier group

typedef short  s16x8 __attribute__((ext_vector_type(8)));
typedef float  fx4   __attribute__((ext_vector_type(4)));
typedef float  fx8   __attribute__((ext_vector_type(8)));
typedef unsigned short u16;
typedef u16    u16x4 __attribute__((ext_vector_type(4)));
typedef unsigned long long u64t;

__device__ __forceinline__ u16 f2bf(float f){
  unsigned u = __float_as_uint(f);
  unsigned r = u + 0x7fffu + ((u >> 16) & 1u);   // RNE
  return (u16)(r >> 16);
}
__device__ __forceinline__ float bf2f(u16 s){ return __uint_as_float(((unsigned)s) << 16); }
__device__ __forceinline__ float sigm(float x){ return 1.0f / (1.0f + __expf(-x)); }
__device__ __forceinline__ float tanh_(float x){
  float ax = fabsf(x);
  float e  = __expf(2.0f * ax);
  float r  = 1.0f - 2.0f / (e + 1.0f);
  return copysignf(r, x);
}
__device__ __forceinline__ fx4 mfma(s16x8 a, s16x8 b, fx4 c){
  return __builtin_amdgcn_mfma_f32_16x16x32_bf16(a, b, c, 0, 0, 0);
}
__device__ __forceinline__ void keepreg(s16x8& v){ asm volatile("" : "+v"(v)); }

// async global->LDS, 16B/lane: LDS dest = wave-uniform base + lane*16
__device__ __forceinline__ void lds_cp16(const u16* g, short* l){
  __builtin_amdgcn_global_load_lds(
      (const __attribute__((address_space(1))) void*)g,
      (__attribute__((address_space(3))) void*)l, 16, 0, 0);
}

// system-scope relaxed atomics: cache-bypass, no cache-maintenance instructions
__device__ __forceinline__ u64t aload64(const u16* p){
  return __hip_atomic_load((const u64t*)p, __ATOMIC_RELAXED, __HIP_MEMORY_SCOPE_SYSTEM);
}
__device__ __forceinline__ void astore32(u16* p, unsigned v){
  __hip_atomic_store((unsigned*)p, v, __ATOMIC_RELAXED, __HIP_MEMORY_SCOPE_SYSTEM);
}
__device__ __forceinline__ unsigned aload32(const unsigned* p){
  return __hip_atomic_load(p, __ATOMIC_RELAXED, __HIP_MEMORY_SCOPE_SYSTEM);
}
__device__ __forceinline__ unsigned afadd(unsigned* p){
  return __hip_atomic_fetch_add(p, 1u, __ATOMIC_RELAXED, __HIP_MEMORY_SCOPE_SYSTEM);
}

// ---------------- prep kernels ----------------
__global__ void cvt_hilo(const float* __restrict__ src, u16* __restrict__ hi,
                         u16* __restrict__ lo, int n4){
  int i      = blockIdx.x * blockDim.x + threadIdx.x;
  int stride = gridDim.x * blockDim.x;
  for (; i < n4; i += stride){
    fx4 v = ((const fx4*)src)[i];
    u16x4 h, l;
    #pragma unroll
    for (int k = 0; k < 4; ++k){
      u16 hh = f2bf(v[k]);
      h[k] = hh;
      l[k] = f2bf(v[k] - bf2f(hh));
    }
    ((u16x4*)hi)[i] = h;
    ((u16x4*)lo)[i] = l;
  }
}

__global__ void vadd(const float* __restrict__ a, const float* __restrict__ b,
                     float* __restrict__ o, int n){
  int i = blockIdx.x * blockDim.x + threadIdx.x;
  if (i < n) o[i] = a[i] + b[i];
}

// ---------------- bulk GEMM: 128x128 tile, hybrid staging, 4 waves ----------
// A rows r = tl*64 + b. AMODE 0: A = fp32 x at [b][c0+tl][KD], reg-convert +
// ds_write staging (r15-proven); AMODE 1: A = hi/lo archive at [b*TC_+tl][KD],
// async global_load_lds staging. B always async global_load_lds.
// LDS layout per 16-row block (1 KB): slot byte = lane*16 — identical for
// ds_write path (sslot = lane*8 shorts) and global_load_lds (base + lane*16).
// OMODE 0: xp out[((tl*4+g)*H + j)*64 + b]; OMODE 1: out[(b*T_+c0+tl)*N + n].
template<int KD, int AMODE, int OMODE>
__global__ __launch_bounds__(256)
void gemm128(const float* __restrict__ Af,
             const u16* __restrict__ Ah, const u16* __restrict__ Al,
             const u16* __restrict__ Bh, const u16* __restrict__ Bl,
             const float* __restrict__ bias,
             float* __restrict__ out, int N, int c0)
{
  __shared__ short As0[4096], As1[4096];   // A hi/lo: 8 blocks x 512 shorts
  __shared__ short Bs0[4096], Bs1[4096];   // B hi/lo
  __shared__ float xt[(OMODE == 0) ? 64 * 130 : 4];

  const int tid  = threadIdx.x;
  const int w    = tid >> 6;
  const int lane = tid & 63;
  const int l15  = lane & 15;
  const int lhi  = lane >> 4;
  const int mb   = blockIdx.x * 128;
  const int nb   = blockIdx.y * 128;

  // staging identity: lane l -> slot l of each block (row16 = l>>2, kc = l&3)
  const int srow  = lane >> 2;             // 0..15
  const int skc   = lane & 3;              // 0..3
  const int sslot = srow * 32 + skc * 8;   // == lane*8 shorts == lane*16 bytes

  fx4 acc[4][4] = {};

  for (int kt = 0; kt < KD / 32; ++kt){
    const int kk = kt * 32 + skc * 8;
    __syncthreads();                       // previous iteration's reads done
    // ---- stage: wave w handles A blocks {2w,2w+1} and B blocks {2w,2w+1} ----
    #pragma unroll
    for (int bi = 0; bi < 2; ++bi){
      const int bl   = 2 * w + bi;
      const int lrow = bl * 16 + srow;
      const int r    = mb + lrow;
      const int b    = r & 63;
      const int tlr  = r >> 6;
      // B: async global->LDS (1 KB per copy, lane*16 pattern)
      const size_t bo = (size_t)(nb + bl * 16 + srow) * KD + kk;
      lds_cp16(Bh + bo, &Bs0[bl * 512]);
      lds_cp16(Bl + bo, &Bs1[bl * 512]);
      if (AMODE == 0){
        // A: fp32 load + convert + ds_write (same slot layout)
        const float* p = Af + ((size_t)b * T_ + c0 + tlr) * KD + kk;
        fx8 v = *reinterpret_cast<const fx8*>(p);
        s16x8 hv, lv;
        #pragma unroll
        for (int q = 0; q < 8; ++q){
          u16 hh = f2bf(v[q]);
          hv[q] = (short)hh;
          lv[q] = (short)f2bf(v[q] - bf2f(hh));
        }
        *reinterpret_cast<s16x8*>(&As0[bl * 512 + sslot]) = hv;
        *reinterpret_cast<s16x8*>(&As1[bl * 512 + sslot]) = lv;
      } else {
        const size_t ao = ((size_t)b * TC_ + tlr) * KD + kk;
        lds_cp16(Ah + ao, &As0[bl * 512]);
        lds_cp16(Al + ao, &As1[bl * 512]);
      }
    }
    __syncthreads();                       // drains vmcnt + lgkm -> LDS ready

    // ---- MFMA: wave quadrant rows (w&1)*64, cols (w>>1)*64 ----
    const int fro = l15 * 32 + lhi * 8;
    s16x8 bhf[4], blf[4];
    #pragma unroll
    for (int j = 0; j < 4; ++j){
      const int bb = ((w >> 1) * 4 + j) * 512 + fro;
      bhf[j] = *reinterpret_cast<const s16x8*>(&Bs0[bb]);
      blf[j] = *reinterpret_cast<const s16x8*>(&Bs1[bb]);
    }
    #pragma unroll
    for (int i = 0; i < 4; ++i){
      const int ab = ((w & 1) * 4 + i) * 512 + fro;
      s16x8 ah = *reinterpret_cast<const s16x8*>(&As0[ab]);
      s16x8 al = *reinterpret_cast<const s16x8*>(&As1[ab]);
      #pragma unroll
      for (int j = 0; j < 4; ++j){
        acc[i][j] = mfma(ah, bhf[j], acc[i][j]);
        acc[i][j] = mfma(ah, blf[j], acc[i][j]);
        acc[i][j] = mfma(al, bhf[j], acc[i][j]);
      }
    }
  }

  if (OMODE == 0){
    // two row-half passes; each half = one tl, 64 b x 128 cols via xt
    #pragma unroll
    for (int p = 0; p < 2; ++p){
      __syncthreads();
      if ((w & 1) == p){
        #pragma unroll
        for (int i = 0; i < 4; ++i)
          #pragma unroll
          for (int j = 0; j < 4; ++j){
            const int col = (w >> 1) * 64 + j * 16 + l15;
            const float bv = bias[nb + col];
            #pragma unroll
            for (int r = 0; r < 4; ++r)
              xt[(i * 16 + lhi * 4 + r) * 130 + col] = acc[i][j][r] + bv;
          }
      }
      __syncthreads();
      const int tlv = (mb >> 6) + p;
      const int b   = tid & 63;
      #pragma unroll
      for (int c = 0; c < 32; ++c){
        const int col = (tid >> 6) + c * 4;
        const int n = nb + col;
        const int g = n >> 10;
        const int jj = n & 1023;
        out[((size_t)(tlv * 4 + g) * H_ + jj) * 64 + b] = xt[b * 130 + col];
      }
    }
  } else {
    #pragma unroll
    for (int j = 0; j < 4; ++j){
      const int n = nb + (w >> 1) * 64 + j * 16 + l15;
      const float bv = bias[n];
      #pragma unroll
      for (int i = 0; i < 4; ++i)
        #pragma unroll
        for (int r = 0; r < 4; ++r){
          const int m  = mb + (w & 1) * 64 + i * 16 + lhi * 4 + r;
          const int b  = m & 63;
          const int tlv = m >> 6;
          out[((size_t)b * T_ + c0 + tlv) * (size_t)N + n] = acc[i][j][r] + bv;
        }
    }
  }
}

// ---------------- two-level grid barrier (relaxed atomics, r7-proven) ----------
__device__ __forceinline__ void gbar(unsigned* bar, int gid, unsigned ep, int ngrp){
  if (afadd(&bar[gid * 32]) == WPG - 1u){
    __hip_atomic_store(&bar[gid * 32], 0u, __ATOMIC_RELAXED, __HIP_MEMORY_SCOPE_SYSTEM);
    if (afadd(&bar[512]) == (unsigned)(ngrp - 1)){
      __hip_atomic_store(&bar[512], 0u, __ATOMIC_RELAXED, __HIP_MEMORY_SCOPE_SYSTEM);
      astore32((u16*)&bar[544], ep);
    } else {
      while (aload32(&bar[544]) != ep) __builtin_amdgcn_s_sleep(1);
    }
    astore32((u16*)&bar[1024 + gid * 32], ep);
  } else {
    while (aload32(&bar[1024 + gid * 32]) != ep) __builtin_amdgcn_s_sleep(1);
  }
}

// ---------------- persistent dual-layer LSTM chunk (r10 config, best) ----------
#define RSTR 577   // LDS row stride floats (col stride 9, coprime with 32 banks)
__global__ __launch_bounds__(512) __attribute__((amdgpu_waves_per_eu(2, 2)))
void lstm_pd(int mode, unsigned ep0, int ngrp,
    const u16* __restrict__ W1h, const u16* __restrict__ W1l,
    const float* __restrict__ xp1, float* __restrict__ cst1,
    u16* __restrict__ hx1h, u16* __restrict__ hx1l,
    u16* __restrict__ ha1h, u16* __restrict__ ha1l,
    const u16* __restrict__ W2h, const u16* __restrict__ W2l,
    const float* __restrict__ xp2, float* __restrict__ cst2,
    u16* __restrict__ hx2h, u16* __restrict__ hx2l,
    u16* __restrict__ ha2h, u16* __restrict__ ha2l,
    unsigned* __restrict__ bar)
{
  __shared__ float red[16 * RSTR];

  const int x8 = blockIdx.x & 7;
  const int q  = blockIdx.x >> 3;
  int part, m4, ghi;
  if (mode == 3){ part = q & 1;    m4 = (q >> 1) & 3; ghi = q >> 3; }
  else          { part = mode - 1; m4 = q & 3;        ghi = q >> 2; }
  const int jb  = (x8 + 8 * ghi) * 32;    // unit base (0..992)
  const int mb  = m4 * 16;                // batch-row base
  const int gid = blockIdx.x >> 4;

  const u16*   Wh  = part ? W2h  : W1h;
  const u16*   Wl  = part ? W2l  : W1l;
  const float* xp  = part ? xp2  : xp1;
  float*       cst = part ? cst2 : cst1;
  u16*         hxh = part ? hx2h : hx1h;
  u16*         hxl = part ? hx2l : hx1l;
  u16*         hah = part ? ha2h : ha1h;
  u16*         hal = part ? ha2l : ha1l;

  const int tid  = threadIdx.x;
  const int lane = tid & 63;
  const int wv   = tid >> 6;              // 0..7 = K slice
  const int l15  = lane & 15;
  const int lhi  = lane >> 4;
  const int kb0  = wv * 128 + lhi * 8;

  size_t wrowR[4], wrowS[4];
  #pragma unroll
  for (int ct = 0; ct < 4; ++ct){
    const int clR = ct * 16 + l15;
    const int clS = (ct + 4) * 16 + l15;
    wrowR[ct] = (size_t)((clR >> 5) * H_ + jb + (clR & 31));
    wrowS[ct] = (size_t)((clS >> 5) * H_ + jb + (clS & 31));
  }

  s16x8 wrh[4][4], wrl[4][4];
  #pragma unroll
  for (int ct = 0; ct < 4; ++ct)
    #pragma unroll
    for (int s = 0; s < 4; ++s){
      const size_t wo = wrowR[ct] * H_ + kb0 + s * 32;
      wrh[ct][s] = *reinterpret_cast<const s16x8*>(Wh + wo);
      wrl[ct][s] = *reinterpret_cast<const s16x8*>(Wl + wo);
      keepreg(wrh[ct][s]);
      keepreg(wrl[ct][s]);
    }

  const int up = tid & 15;
  const int mm = tid >> 4;                // 0..15 when tid<256
  const int u0 = 2 * up;
  const int j0 = jb + u0;
  const int eb = mb + mm;
  float cva = 0.0f, cvb = 0.0f;
  if (tid < 256){
    cva = cst[(size_t)j0 * B_ + eb];
    cvb = cst[(size_t)(j0 + 1) * B_ + eb];
  }

  for (int tl = 0; tl < TC_; ++tl){
    const int par = tl & 1;
    const u16* rph = hxh + par * (64 * H_);
    const u16* rpl = hxl + par * (64 * H_);
    u16* nph = hxh + (par ^ 1) * (64 * H_);
    u16* npl = hxl + (par ^ 1) * (64 * H_);

    float xq0[4], xq1[4];
    if (tid < 256){
      #pragma unroll
      for (int g = 0; g < 4; ++g){
        const float* xr = xp + ((size_t)(tl * 4 + g) * H_ + j0) * 64 + eb;
        xq0[g] = xr[0];
        xq1[g] = xr[64];
      }
    }

    fx4 acc[8] = {};
    #pragma unroll
    for (int s = 0; s < 4; ++s){
      const int kb = kb0 + s * 32;
      const u16* ph = rph + (size_t)(mb + l15) * H_ + kb;
      const u16* pl = rpl + (size_t)(mb + l15) * H_ + kb;
      union { u64t u[2]; s16x8 v; } ua, ul;
      ua.u[0] = aload64(ph);  ua.u[1] = aload64(ph + 4);
      ul.u[0] = aload64(pl);  ul.u[1] = aload64(pl + 4);
      #pragma unroll
      for (int ct = 0; ct < 4; ++ct){
        acc[ct] = mfma(ua.v, wrh[ct][s], acc[ct]);
        acc[ct] = mfma(ua.v, wrl[ct][s], acc[ct]);
        acc[ct] = mfma(ul.v, wrh[ct][s], acc[ct]);
      }
      #pragma unroll
      for (int ct = 0; ct < 4; ++ct){
        const size_t wo = wrowS[ct] * H_ + kb;
        s16x8 bh = *reinterpret_cast<const s16x8*>(Wh + wo);
        s16x8 bl = *reinterpret_cast<const s16x8*>(Wl + wo);
        acc[4 + ct] = mfma(ua.v, bh, acc[4 + ct]);
        acc[4 + ct] = mfma(ua.v, bl, acc[4 + ct]);
        acc[4 + ct] = mfma(ul.v, bh, acc[4 + ct]);
      }
    }

    #pragma unroll
    for (int ct = 0; ct < 4; ++ct)
      #pragma unroll
      for (int r = 0; r < 4; ++r)
        red[(lhi * 4 + r) * RSTR + (ct * 16 + l15) * 9 + wv] = acc[ct][r];
    __syncthreads();
    float i0s = 0, i1s = 0, f0s = 0, f1s = 0;
    if (tid < 256){
      const float* r0 = red + mm * RSTR + (u0) * 9;
      const float* r1 = red + mm * RSTR + (u0 + 1) * 9;
      const float* r2 = red + mm * RSTR + (32 + u0) * 9;
      const float* r3 = red + mm * RSTR + (32 + u0 + 1) * 9;
      #pragma unroll
      for (int w = 0; w < 8; ++w){
        i0s += r0[w]; i1s += r1[w]; f0s += r2[w]; f1s += r3[w];
      }
    }
    __syncthreads();

    #pragma unroll
    for (int ct = 0; ct < 4; ++ct)
      #pragma unroll
      for (int r = 0; r < 4; ++r)
        red[(lhi * 4 + r) * RSTR + (ct * 16 + l15) * 9 + wv] = acc[4 + ct][r];
    __syncthreads();

    if (tid < 256){
      float g0s = 0, g1s = 0, o0s = 0, o1s = 0;
      const float* r0 = red + mm * RSTR + (u0) * 9;
      const float* r1 = red + mm * RSTR + (u0 + 1) * 9;
      const float* r2 = red + mm * RSTR + (32 + u0) * 9;
      const float* r3 = red + mm * RSTR + (32 + u0 + 1) * 9;
      #pragma unroll
      for (int w = 0; w < 8; ++w){
        g0s += r0[w]; g1s += r1[w]; o0s += r2[w]; o1s += r3[w];
      }
      float iv = sigm (i0s + xq0[0]);
      float fv = sigm (f0s + xq0[1]);
      float gv = tanh_(g0s + xq0[2]);
      float ov = sigm (o0s + xq0[3]);
      float cn = fv * cva + iv * gv;
      float h0 = ov * tanh_(cn);
      cva = cn;
      iv = sigm (i1s + xq1[0]);
      fv = sigm (f1s + xq1[1]);
      gv = tanh_(g1s + xq1[2]);
      ov = sigm (o1s + xq1[3]);
      cn = fv * cvb + iv * gv;
      float h1 = ov * tanh_(cn);
      cvb = cn;

      u16 h0h = f2bf(h0), h0l = f2bf(h0 - bf2f(h0h));
      u16 h1h = f2bf(h1), h1l = f2bf(h1 - bf2f(h1h));
      astore32(nph + (size_t)eb * H_ + j0, (unsigned)h0h | ((unsigned)h1h << 16));
      astore32(npl + (size_t)eb * H_ + j0, (unsigned)h0l | ((unsigned)h1l << 16));
      const size_t ai = ((size_t)eb * TC_ + tl) * H_ + j0;
      *(unsigned*)(hah + ai) = (unsigned)h0h | ((unsigned)h1h << 16);
      *(unsigned*)(hal + ai) = (unsigned)h0l | ((unsigned)h1l << 16);
    }

    __syncthreads();                      // drains vmcnt before signal
    if (tid == 0) gbar(bar, gid, ep0 + tl + 1, ngrp);
    __syncthreads();
  }
  if (tid < 256){
    cst[(size_t)j0 * B_ + eb]       = cva;
    cst[(size_t)(j0 + 1) * B_ + eb] = cvb;
  }
}

// ---------------- host launch ----------------
extern "C" void kernel_launch(void* const* d_in, const int* in_sizes, int n_in,
                              void* d_out, int out_size, void* d_ws, size_t ws_size,
                              hipStream_t stream)
{
  const float* x    = (const float*)d_in[0];
  const float* Wih1 = (const float*)d_in[1];
  const float* Whh1 = (const float*)d_in[2];
  const float* bih1 = (const float*)d_in[3];
  const float* bhh1 = (const float*)d_in[4];
  const float* Wih2 = (const float*)d_in[5];
  const float* Whh2 = (const float*)d_in[6];
  const float* bih2 = (const float*)d_in[7];
  const float* bhh2 = (const float*)d_in[8];
  const float* fcW  = (const float*)d_in[9];
  const float* fcb  = (const float*)d_in[10];
  float* out = (float*)d_out;
  (void)in_sizes; (void)n_in; (void)out_size; (void)ws_size;

  char* base = (char*)d_ws;
  size_t off = 0;
  auto alloc = [&](size_t bytes) -> void* {
    void* p = base + off;
    off = (off + bytes + 255) & ~(size_t)255;
    return p;
  };
  u16* Wih1_hi = (u16*)alloc((size_t)G4_ * I_ * 2);
  u16* Wih1_lo = (u16*)alloc((size_t)G4_ * I_ * 2);
  u16* Whh1_hi = (u16*)alloc((size_t)G4_ * H_ * 2);
  u16* Whh1_lo = (u16*)alloc((size_t)G4_ * H_ * 2);
  u16* Wih2_hi = (u16*)alloc((size_t)G4_ * H_ * 2);
  u16* Wih2_lo = (u16*)alloc((size_t)G4_ * H_ * 2);
  u16* Whh2_hi = (u16*)alloc((size_t)G4_ * H_ * 2);
  u16* Whh2_lo = (u16*)alloc((size_t)G4_ * H_ * 2);
  u16* fcW_hi  = (u16*)alloc((size_t)O_ * H_ * 2);
  u16* fcW_lo  = (u16*)alloc((size_t)O_ * H_ * 2);
  float* bsum1 = (float*)alloc((size_t)G4_ * 4);
  float* bsum2 = (float*)alloc((size_t)G4_ * 4);
  float* cst1  = (float*)alloc((size_t)B_ * H_ * 4);
  float* cst2  = (float*)alloc((size_t)B_ * H_ * 4);
  u16* hx1h = (u16*)alloc((size_t)2 * B_ * H_ * 2);
  u16* hx1l = (u16*)alloc((size_t)2 * B_ * H_ * 2);
  u16* hx2h = (u16*)alloc((size_t)2 * B_ * H_ * 2);
  u16* hx2l = (u16*)alloc((size_t)2 * B_ * H_ * 2);
  u16* h1s_hi = (u16*)alloc((size_t)B_ * TC_ * H_ * 2);
  u16* h1s_lo = (u16*)alloc((size_t)B_ * TC_ * H_ * 2);
  u16* h2s_hi = (u16*)alloc((size_t)B_ * TC_ * H_ * 2);
  u16* h2s_lo = (u16*)alloc((size_t)B_ * TC_ * H_ * 2);
  float* xp1  = (float*)alloc((size_t)TC_ * G4_ * B_ * 4);
  float* xp2  = (float*)alloc((size_t)TC_ * G4_ * B_ * 4);
  unsigned* bar = (unsigned*)alloc(2048 * 4);

  // ---- prep ----
  cvt_hilo<<<512, 256, 0, stream>>>(Wih1, Wih1_hi, Wih1_lo, G4_ * I_ / 4);
  cvt_hilo<<<512, 256, 0, stream>>>(Whh1, Whh1_hi, Whh1_lo, G4_ * H_ / 4);
  cvt_hilo<<<512, 256, 0, stream>>>(Wih2, Wih2_hi, Wih2_lo, G4_ * H_ / 4);
  cvt_hilo<<<512, 256, 0, stream>>>(Whh2, Whh2_hi, Whh2_lo, G4_ * H_ / 4);
  cvt_hilo<<<256, 256, 0, stream>>>(fcW,  fcW_hi,  fcW_lo,  O_ * H_ / 4);
  vadd<<<16, 256, 0, stream>>>(bih1, bhh1, bsum1, G4_);
  vadd<<<16, 256, 0, stream>>>(bih2, bhh2, bsum2, G4_);

  hipMemsetAsync(cst1, 0, (size_t)B_ * H_ * 4, stream);
  hipMemsetAsync(cst2, 0, (size_t)B_ * H_ * 4, stream);
  hipMemsetAsync(hx1h, 0, (size_t)2 * B_ * H_ * 2, stream);
  hipMemsetAsync(hx1l, 0, (size_t)2 * B_ * H_ * 2, stream);
  hipMemsetAsync(hx2h, 0, (size_t)2 * B_ * H_ * 2, stream);
  hipMemsetAsync(hx2l, 0, (size_t)2 * B_ * H_ * 2, stream);
  hipMemsetAsync(bar,  0, 2048 * 4, stream);

  const dim3 gX(32, 32);   // 128x128 tiles: M=4096, N=4096
  const dim3 gF(32, 4);    // N=512

  gemm128<I_, 0, 0><<<gX, 256, 0, stream>>>(
      x, nullptr, nullptr, Wih1_hi, Wih1_lo, bsum1, xp1, G4_, 0);

  unsigned ep = 0;
  for (int c = 0; c <= NCH; ++c){
    const int mode = ((c < NCH) ? 1 : 0) | ((c >= 1) ? 2 : 0);
    const int nwg  = (mode == 3) ? 256 : 128;
    int ngrp = nwg / WPG;
    {
      void* args[] = { (void*)&mode, (void*)&ep, (void*)&ngrp,
                       (void*)&Whh1_hi, (void*)&Whh1_lo, (void*)&xp1, (void*)&cst1,
                       (void*)&hx1h, (void*)&hx1l, (void*)&h1s_hi, (void*)&h1s_lo,
                       (void*)&Whh2_hi, (void*)&Whh2_lo, (void*)&xp2, (void*)&cst2,
                       (void*)&hx2h, (void*)&hx2l, (void*)&h2s_hi, (void*)&h2s_lo,
                       (void*)&bar };
      hipLaunchCooperativeKernel((const void*)lstm_pd, dim3(nwg), dim3(512),
                                 args, 0, stream);
      ep += TC_;
    }
    if (c < NCH)
      gemm128<H_, 1, 0><<<gX, 256, 0, stream>>>(
          nullptr, h1s_hi, h1s_lo, Wih2_hi, Wih2_lo, bsum2, xp2, G4_, 0);
    if (c + 1 < NCH)
      gemm128<I_, 0, 0><<<gX, 256, 0, stream>>>(
          x, nullptr, nullptr, Wih1_hi, Wih1_lo, bsum1, xp1, G4_, (c + 1) * TC_);
    if (c >= 1)
      gemm128<H_, 1, 1><<<gF, 256, 0, stream>>>(
          nullptr, h2s_hi, h2s_lo, fcW_hi, fcW_lo, fcb, out, O_, (c - 1) * TC_);
  }
}